// Round 8
// baseline (585.952 us; speedup 1.0000x reference)
//
#include <hip/hip_runtime.h>
#include <hip/hip_fp16.h>

// Problem constants (fixed by setup_inputs / GTLModuleV1)
#define BATCH 4
#define CHAN  144
#define NPTS  16384
#define KNN   16
#define GRP   9
#define DIM   16
#define ROWU  (GRP * DIM)        // 144 uint32 per point = 576 B row
#define PCHUNK 64                // chunks per (b,g) pair -> 36*64 = 2304 blocks
#define NPAIR (BATCH * GRP)      // 36

#define TT 32

typedef __attribute__((ext_vector_type(2))) _Float16 h2v;
typedef __attribute__((ext_vector_type(4))) float f4v;   // clang vector: nt ops OK
typedef __attribute__((ext_vector_type(4))) int   i4v;   // clang vector: nt ops OK
__device__ __forceinline__ h2v as_h2(unsigned int u) {
  union { unsigned int u; h2v h; } c; c.u = u; return c.h;
}

// DPP helpers: quad_perm ops are VALU (no LDS pipe, ~4cy vs ~40cy bpermute).
template<int J>  // broadcast quad-lane J to all 4 lanes of the quad
__device__ __forceinline__ int ibcast(int v) {
  return __builtin_amdgcn_update_dpp(0, v, (J) * 0x55, 0xF, 0xF, true);
}
template<int C>  // C=0xB1: xor1 swap; C=0x4E: xor2 swap (within quad)
__device__ __forceinline__ float fxor(float x) {
  int r = __builtin_amdgcn_update_dpp(0, __builtin_bit_cast(int, x), C, 0xF, 0xF, true);
  return __builtin_bit_cast(float, r);
}

// (C,N) fp32 q,v -> (N, 144 uints): per group g, uint 2i = h2(k_{2i},k_{2i+1}),
// uint 2i+1 = h2(v_{2i},v_{2i+1}). Each (g,m) slice = 64 B; a uint4 at uint
// offset 16g+4d = dims 4d..4d+3 of key AND val (k01,v01,k23,v23 pattern).
__global__ __launch_bounds__(256) void pack_qv_kernel(
    const float* __restrict__ q, const float* __restrict__ v,
    unsigned int* __restrict__ qvT) {
  __shared__ float tq[TT][TT + 1];
  __shared__ float tv[TT][TT + 1];
  const int b = blockIdx.z;
  const float* qb = q + (size_t)b * CHAN * NPTS;
  const float* vb = v + (size_t)b * CHAN * NPTS;
  unsigned int* out = qvT + (size_t)b * NPTS * ROWU;
  const int n0 = blockIdx.x * TT;
  const int c0 = blockIdx.y * TT;
  const int t = threadIdx.x;

  {  // load both tiles: float4 along n (coalesced)
    const int cl = t >> 3, nq = (t & 7) * 4;
    const int c = c0 + cl;
    if (c < CHAN) {
      const float4 a = *(const float4*)&qb[(size_t)c * NPTS + n0 + nq];
      tq[cl][nq + 0] = a.x; tq[cl][nq + 1] = a.y;
      tq[cl][nq + 2] = a.z; tq[cl][nq + 3] = a.w;
      const float4 w = *(const float4*)&vb[(size_t)c * NPTS + n0 + nq];
      tv[cl][nq + 0] = w.x; tv[cl][nq + 1] = w.y;
      tv[cl][nq + 2] = w.z; tv[cl][nq + 3] = w.w;
    }
  }
  __syncthreads();
  {  // store packed dim-pairs: uint4 along c (coalesced 128B per 8-thr cluster)
    const int nl = t >> 3, cq = (t & 7) * 4;
    const int c = c0 + cq;   // multiple of 4
    if (c < CHAN) {
      const int g = c >> 4, r = c & 15;   // r in {0,4,8,12}
      __half2 k01 = __halves2half2(__float2half_rn(tq[cq + 0][nl]),
                                   __float2half_rn(tq[cq + 1][nl]));
      __half2 v01 = __halves2half2(__float2half_rn(tv[cq + 0][nl]),
                                   __float2half_rn(tv[cq + 1][nl]));
      __half2 k23 = __halves2half2(__float2half_rn(tq[cq + 2][nl]),
                                   __float2half_rn(tq[cq + 3][nl]));
      __half2 v23 = __halves2half2(__float2half_rn(tv[cq + 2][nl]),
                                   __float2half_rn(tv[cq + 3][nl]));
      *(uint4*)&out[(size_t)(n0 + nl) * ROWU + g * 16 + r] =
          make_uint4(*(unsigned int*)&k01, *(unsigned int*)&v01,
                     *(unsigned int*)&k23, *(unsigned int*)&v23);
    }
  }
}

// R5 quad-per-point: wave = 16 points x 4 dim-quad lanes; ONE uint4 gather
// per (point,neighbor); DPP quad ops for id-bcast + dot butterfly; no-max
// softmax with fused value accumulation.
// R8 de-privatization: at PCHUNK>=32 a block's lcent got 0.5 hits/bin --
// the 64KB LDS privatization reduced NOTHING while (a) capping residency
// at 2 blocks/CU (occupancy 35%, VALUBusy 17%: latency-starved) and (b)
// costing init + 9.4M LDS RMWs + an 8.7M-global-RMW bursty flush. Delete
// it: centrality weights atomicAdd straight into the pair's 64KB cent
// slice (L2-hot on its own XCD; same total RMW count, smooth not bursty).
// LDS=0 -> occupancy VGPR-capped (launch_bounds(512,8), 56 VGPR -> up to
// 32 waves/CU, 4x). Residency invariant kept: PCHUNK 64 -> 128 resident
// blocks/XCD / 64 chunks = 2 pairs = 2MB gather slices per 4MB L2.
__global__ __launch_bounds__(512, 8) void gtl_kernel(
    const unsigned int* __restrict__ qvT,  // (B, N, ROWU) packed
    const int*   __restrict__ idx,         // (B, N, K)
    float* __restrict__ feat,              // (B, C, N)
    float* __restrict__ cent)              // (NPAIR, NPTS) pre-zeroed
{
  // ---- XCD-partitioned decode: grid 2304 = 8*288, no dummies ----
  const int i = blockIdx.x;
  const int x = i & 7, sblk = i >> 3;     // sblk in 0..287
  int pair, chunk;
  if (sblk < 256) { pair = x + 8 * (sblk >> 6); chunk = sblk & 63; }
  else            { pair = 32 + (x >> 1); chunk = (sblk - 256) + 32 * (x & 1); }
  const int b = pair / GRP;
  const int g = pair - b * GRP;

  // chunk -> 2 groups of 128 points (128 groups per pair, 64 chunks x 2)
  const int NG = 2;
  const int gstart = 2 * chunk;

  const int tid  = threadIdx.x;
  const int lane = tid & 63;
  const int wv   = tid >> 6;        // 8 waves / block
  const int slot = lane >> 2;       // point within wave [0,16)
  const int d    = lane & 3;        // dim-quad within group [0,4)

  // Uniform (SGPR) byte bases; per-lane 32-bit offsets (qvT slice < 9.4 MB).
  const char* qvb  = (const char*)qvT + (size_t)b * NPTS * (ROWU * 4);
  const char* idxB = (const char*)idx + (size_t)b * NPTS * (KNN * 4);
  float* cb = cent + (size_t)pair * NPTS;
  const unsigned laneB  = (unsigned)(g * 64 + d * 16);   // g*DIM*4 + 4*d*4
  const unsigned idxoff = (unsigned)(d * 16);

  // ---- prologue: iteration 0's idx quad + q fragment ----
  int n = gstart * 128 + wv * 16 + slot;
  i4v idq = __builtin_nontemporal_load(
      (const i4v*)(idxB + (unsigned)n * 64u + idxoff));   // ids 4d..4d+3
  uint4 qq = *(const uint4*)(qvb + (unsigned)n * (ROWU * 4u) + laneB);

  for (int it = 0; it < NG; ++it) {
    const h2v q01 = as_h2(qq.x);
    const h2v q23 = as_h2(qq.z);

    // ---- burst: 16 uint4 gathers = 16 points x 16 neighbors in flight ----
    // Neighbor K's id lives in quad-lane (K>>2), component (K&3): DPP bcast.
    uint4 kvp[KNN];
#define GSTEP(K)                                                             \
    {                                                                        \
      const int mk = ibcast<((K) >> 2)>(                                     \
          ((K) & 3) == 0 ? idq.x : ((K) & 3) == 1 ? idq.y                    \
                         : ((K) & 3) == 2 ? idq.z : idq.w);                  \
      kvp[K] = *(const uint4*)(qvb + (unsigned)mk * (ROWU * 4u) + laneB);    \
    }
    GSTEP(0)  GSTEP(1)  GSTEP(2)  GSTEP(3)
    GSTEP(4)  GSTEP(5)  GSTEP(6)  GSTEP(7)
    GSTEP(8)  GSTEP(9)  GSTEP(10) GSTEP(11)
    GSTEP(12) GSTEP(13) GSTEP(14) GSTEP(15)
#undef GSTEP

    // ---- prefetch next iteration's idx quad + q fragment under the flight ----
    const int itn = (it + 1 < NG) ? it + 1 : it;   // clamp: no OOB
    const int nn = (gstart + itn) * 128 + wv * 16 + slot;
    const i4v idqn = __builtin_nontemporal_load(
        (const i4v*)(idxB + (unsigned)nn * 64u + idxoff));
    const uint4 qqn = *(const uint4*)(qvb + (unsigned)nn * (ROWU * 4u) + laneB);

    // Pin: everything above issues before anything below schedules.
    __builtin_amdgcn_sched_barrier(0);

    // ---- consume in arrival order: score (fdot2 + 2-level DPP butterfly),
    //      no-max exp, fused value accumulation. kvp[K] dies per step. ----
    float p[KNN];
    float sum = 0.f, a0 = 0.f, a1 = 0.f, a2 = 0.f, a3 = 0.f;
#define CSTEP(K)                                                             \
    {                                                                        \
      float s = __builtin_amdgcn_fdot2(as_h2(kvp[K].x), q01, 0.f, false);    \
      s = __builtin_amdgcn_fdot2(as_h2(kvp[K].z), q23, s, false);            \
      s += fxor<0xB1>(s);                                                    \
      s += fxor<0x4E>(s);                                                    \
      const float e = __expf(s);                                             \
      p[K] = e; sum += e;                                                    \
      const float2 v01 = __half22float2(*(const __half2*)&kvp[K].y);         \
      const float2 v23 = __half22float2(*(const __half2*)&kvp[K].w);         \
      a0 += e * v01.x; a1 += e * v01.y; a2 += e * v23.x; a3 += e * v23.y;    \
    }
    CSTEP(0)  CSTEP(1)  CSTEP(2)  CSTEP(3)
    CSTEP(4)  CSTEP(5)  CSTEP(6)  CSTEP(7)
    CSTEP(8)  CSTEP(9)  CSTEP(10) CSTEP(11)
    CSTEP(12) CSTEP(13) CSTEP(14) CSTEP(15)
#undef CSTEP

    const float inv = 1.f / sum;

    // centrality: lane d scatters neighbors k=4d..4d+3 (ids = idq.x..w)
    // straight into the pair's cent slice (L2-resident on this XCD).
    // p[] indices are compile-time; select over runtime d via cndmask.
    const float w0 = (d == 0 ? p[0] : d == 1 ? p[4] : d == 2 ? p[8]  : p[12]) * inv;
    const float w1 = (d == 0 ? p[1] : d == 1 ? p[5] : d == 2 ? p[9]  : p[13]) * inv;
    const float w2 = (d == 0 ? p[2] : d == 1 ? p[6] : d == 2 ? p[10] : p[14]) * inv;
    const float w3 = (d == 0 ? p[3] : d == 1 ? p[7] : d == 2 ? p[11] : p[15]) * inv;
    atomicAdd(&cb[idq.x], w0);
    atomicAdd(&cb[idq.y], w1);
    atomicAdd(&cb[idq.z], w2);
    atomicAdd(&cb[idq.w], w3);

    // feat write: dims 4d..4d+3 of point n; nt: don't pollute the L2 slice
    float* fb = feat + ((size_t)b * CHAN + g * DIM + 4 * d) * NPTS + n;
    __builtin_nontemporal_store(a0 * inv, fb);
    __builtin_nontemporal_store(a1 * inv, fb + NPTS);
    __builtin_nontemporal_store(a2 * inv, fb + 2 * NPTS);
    __builtin_nontemporal_store(a3 * inv, fb + 3 * NPTS);

    // rotate prefetched state
    n = nn; idq = idqn; qq = qqn;
  }
}

extern "C" void kernel_launch(void* const* d_in, const int* in_sizes, int n_in,
                              void* d_out, int out_size, void* d_ws, size_t ws_size,
                              hipStream_t stream) {
  const float* q   = (const float*)d_in[0];   // queryandkey (B,C,N)
  const float* v   = (const float*)d_in[1];   // value (B,C,N)
  const int*   idx = (const int*)d_in[2];     // idx_knn (B,N,K)

  float* feat = (float*)d_out;                       // (B,C,N)
  float* cent = feat + (size_t)BATCH * CHAN * NPTS;  // (B,G,N)

  unsigned int* qvT = (unsigned int*)d_ws;           // (B,N,ROWU) packed

  // 0) zero cent (stream-ordered; gtl accumulates into it atomically)
  hipMemsetAsync(cent, 0, (size_t)NPAIR * NPTS * sizeof(float), stream);

  // 1) pack q,v into dim-pair interleaved fp16 rows
  dim3 tg(NPTS / TT, (CHAN + TT - 1) / TT, BATCH);
  pack_qv_kernel<<<tg, 256, 0, stream>>>(q, v, qvT);

  // 2) main fused kernel: 2304 blocks x 512 threads, NO LDS, XCD swizzle;
  //    2 resident pairs per XCD (2MB gather slices) at 4x occupancy
  gtl_kernel<<<NPAIR * PCHUNK, 512, 0, stream>>>(qvT, idx, feat, cent);
}

// Round 9
// 506.742 us; speedup vs baseline: 1.1563x; 1.1563x over previous
//
#include <hip/hip_runtime.h>
#include <hip/hip_fp16.h>

// Problem constants (fixed by setup_inputs / GTLModuleV1)
#define BATCH 4
#define CHAN  144
#define NPTS  16384
#define KNN   16
#define GRP   9
#define DIM   16
#define ROWU  (GRP * DIM)        // 144 uint32 per point = 576 B row
#define PCHUNK 16                // chunks per (b,g) pair -> 36*16 = 576 blocks
#define NPAIR (BATCH * GRP)      // 36

#define TT 32

typedef __attribute__((ext_vector_type(2))) _Float16 h2v;
typedef __attribute__((ext_vector_type(4))) float f4v;   // clang vector: nt ops OK
typedef __attribute__((ext_vector_type(4))) int   i4v;   // clang vector: nt ops OK
__device__ __forceinline__ h2v as_h2(unsigned int u) {
  union { unsigned int u; h2v h; } c; c.u = u; return c.h;
}

// DPP helpers: quad_perm ops are VALU (no LDS pipe, ~4cy vs ~40cy bpermute).
template<int J>  // broadcast quad-lane J to all 4 lanes of the quad
__device__ __forceinline__ int ibcast(int v) {
  return __builtin_amdgcn_update_dpp(0, v, (J) * 0x55, 0xF, 0xF, true);
}
template<int C>  // C=0xB1: xor1 swap; C=0x4E: xor2 swap (within quad)
__device__ __forceinline__ float fxor(float x) {
  int r = __builtin_amdgcn_update_dpp(0, __builtin_bit_cast(int, x), C, 0xF, 0xF, true);
  return __builtin_bit_cast(float, r);
}

// (C,N) fp32 q,v -> (N, 144 uints): per group g, uint 2i = h2(k_{2i},k_{2i+1}),
// uint 2i+1 = h2(v_{2i},v_{2i+1}). Each (g,m) slice = 64 B; a uint4 at uint
// offset 16g+4d = dims 4d..4d+3 of key AND val (k01,v01,k23,v23 pattern).
__global__ __launch_bounds__(256) void pack_qv_kernel(
    const float* __restrict__ q, const float* __restrict__ v,
    unsigned int* __restrict__ qvT) {
  __shared__ float tq[TT][TT + 1];
  __shared__ float tv[TT][TT + 1];
  const int b = blockIdx.z;
  const float* qb = q + (size_t)b * CHAN * NPTS;
  const float* vb = v + (size_t)b * CHAN * NPTS;
  unsigned int* out = qvT + (size_t)b * NPTS * ROWU;
  const int n0 = blockIdx.x * TT;
  const int c0 = blockIdx.y * TT;
  const int t = threadIdx.x;

  {  // load both tiles: float4 along n (coalesced)
    const int cl = t >> 3, nq = (t & 7) * 4;
    const int c = c0 + cl;
    if (c < CHAN) {
      const float4 a = *(const float4*)&qb[(size_t)c * NPTS + n0 + nq];
      tq[cl][nq + 0] = a.x; tq[cl][nq + 1] = a.y;
      tq[cl][nq + 2] = a.z; tq[cl][nq + 3] = a.w;
      const float4 w = *(const float4*)&vb[(size_t)c * NPTS + n0 + nq];
      tv[cl][nq + 0] = w.x; tv[cl][nq + 1] = w.y;
      tv[cl][nq + 2] = w.z; tv[cl][nq + 3] = w.w;
    }
  }
  __syncthreads();
  {  // store packed dim-pairs: uint4 along c (coalesced 128B per 8-thr cluster)
    const int nl = t >> 3, cq = (t & 7) * 4;
    const int c = c0 + cq;   // multiple of 4
    if (c < CHAN) {
      const int g = c >> 4, r = c & 15;   // r in {0,4,8,12}
      __half2 k01 = __halves2half2(__float2half_rn(tq[cq + 0][nl]),
                                   __float2half_rn(tq[cq + 1][nl]));
      __half2 v01 = __halves2half2(__float2half_rn(tv[cq + 0][nl]),
                                   __float2half_rn(tv[cq + 1][nl]));
      __half2 k23 = __halves2half2(__float2half_rn(tq[cq + 2][nl]),
                                   __float2half_rn(tq[cq + 3][nl]));
      __half2 v23 = __halves2half2(__float2half_rn(tv[cq + 2][nl]),
                                   __float2half_rn(tv[cq + 3][nl]));
      *(uint4*)&out[(size_t)(n0 + nl) * ROWU + g * 16 + r] =
          make_uint4(*(unsigned int*)&k01, *(unsigned int*)&v01,
                     *(unsigned int*)&k23, *(unsigned int*)&v23);
    }
  }
}

// R5 quad-per-point core: quad = point (4 dim-quad lanes); ONE uint4 gather
// per (point,neighbor); DPP id-bcast + 2-level DPP dot butterfly; no-max
// softmax with fused value accumulation. LDS-privatized cent (R8 lesson:
// device-scope global atomics resolve PAST the non-coherent per-XCD L2 —
// 9.4M RMWs became 597MB of fabric writes, 4x slowdown. LDS RMW + bulk
// non-atomic part flush is mandatory, even at ~0.5 hits/bin).
// R9 amortization: per-block fixed cost F (64KB lcent init + flush) is
// real: fit from R5/R7 gives F~30ns/block at 512thr, core ~80us. 1024-thr
// blocks + PCHUNK=16 (8 groups/block, 2 groups/iteration) halve F and cut
// block count 756->576; also 2 blocks x 16 waves = 32 waves/CU (2x waves
// vs R5) — tests the occupancy lever on gather in-flight capacity without
// R8's atomic poison. Grid 576 = 8*72, exact XCD decode, no dummies.
__global__ __launch_bounds__(1024, 8) void gtl_kernel(
    const unsigned int* __restrict__ qvT,  // (B, N, ROWU) packed
    const int*   __restrict__ idx,         // (B, N, K)
    float* __restrict__ feat,              // (B, C, N)
    float* __restrict__ part)              // (NPAIR, PCHUNK, NPTS)
{
  // ---- XCD-partitioned decode: grid 576 = 8*72, no dummies ----
  const int i = blockIdx.x;
  const int x = i & 7, sblk = i >> 3;     // sblk in 0..71
  int pair, chunk;
  if (sblk < 64) { pair = x + 8 * (sblk >> 4); chunk = sblk & 15; }
  else           { pair = 32 + (x >> 1); chunk = (sblk - 64) + 8 * (x & 1); }
  const int b = pair / GRP;
  const int g = pair - b * GRP;

  __shared__ float lcent[NPTS];     // 64 KB private cent[b,g,:]
  const int tid = threadIdx.x;

  f4v* l4 = (f4v*)lcent;
  #pragma unroll
  for (int ii = 0; ii < NPTS / 4 / 1024; ++ii)
    l4[ii * 1024 + tid] = (f4v){0.f, 0.f, 0.f, 0.f};
  __syncthreads();

  // chunk -> 8 groups of 128 points; 16 waves process 2 groups/iteration.
  const int NG = 4;                 // 4 iterations x 256 points = 1024
  const int nbase = chunk * 1024;

  const int lane = tid & 63;
  const int wv   = tid >> 6;        // 16 waves / block
  const int slot = lane >> 2;       // point within wave [0,16)
  const int d    = lane & 3;        // dim-quad within group [0,4)

  // Uniform (SGPR) byte bases; per-lane 32-bit offsets (qvT slice < 9.4 MB).
  const char* qvb  = (const char*)qvT + (size_t)b * NPTS * (ROWU * 4);
  const char* idxB = (const char*)idx + (size_t)b * NPTS * (KNN * 4);
  const unsigned laneB  = (unsigned)(g * 64 + d * 16);   // g*DIM*4 + 4*d*4
  const unsigned idxoff = (unsigned)(d * 16);

  // ---- prologue: iteration 0's idx quad + q fragment ----
  int n = nbase + wv * 16 + slot;
  i4v idq = __builtin_nontemporal_load(
      (const i4v*)(idxB + (unsigned)n * 64u + idxoff));   // ids 4d..4d+3
  uint4 qq = *(const uint4*)(qvb + (unsigned)n * (ROWU * 4u) + laneB);

  for (int it = 0; it < NG; ++it) {
    const h2v q01 = as_h2(qq.x);
    const h2v q23 = as_h2(qq.z);

    // ---- burst: 16 uint4 gathers = 16 points x 16 neighbors in flight ----
    // Neighbor K's id lives in quad-lane (K>>2), component (K&3): DPP bcast.
    uint4 kvp[KNN];
#define GSTEP(K)                                                             \
    {                                                                        \
      const int mk = ibcast<((K) >> 2)>(                                     \
          ((K) & 3) == 0 ? idq.x : ((K) & 3) == 1 ? idq.y                    \
                         : ((K) & 3) == 2 ? idq.z : idq.w);                  \
      kvp[K] = *(const uint4*)(qvb + (unsigned)mk * (ROWU * 4u) + laneB);    \
    }
    GSTEP(0)  GSTEP(1)  GSTEP(2)  GSTEP(3)
    GSTEP(4)  GSTEP(5)  GSTEP(6)  GSTEP(7)
    GSTEP(8)  GSTEP(9)  GSTEP(10) GSTEP(11)
    GSTEP(12) GSTEP(13) GSTEP(14) GSTEP(15)
#undef GSTEP

    // ---- prefetch next iteration's idx quad + q fragment under the flight ----
    const int itn = (it + 1 < NG) ? it + 1 : it;   // clamp: no OOB
    const int nn = nbase + itn * 256 + wv * 16 + slot;
    const i4v idqn = __builtin_nontemporal_load(
        (const i4v*)(idxB + (unsigned)nn * 64u + idxoff));
    const uint4 qqn = *(const uint4*)(qvb + (unsigned)nn * (ROWU * 4u) + laneB);

    // Pin: everything above issues before anything below schedules.
    __builtin_amdgcn_sched_barrier(0);

    // ---- consume in arrival order: score (fdot2 + 2-level DPP butterfly),
    //      no-max exp, fused value accumulation. kvp[K] dies per step. ----
    float p[KNN];
    float sum = 0.f, a0 = 0.f, a1 = 0.f, a2 = 0.f, a3 = 0.f;
#define CSTEP(K)                                                             \
    {                                                                        \
      float s = __builtin_amdgcn_fdot2(as_h2(kvp[K].x), q01, 0.f, false);    \
      s = __builtin_amdgcn_fdot2(as_h2(kvp[K].z), q23, s, false);            \
      s += fxor<0xB1>(s);                                                    \
      s += fxor<0x4E>(s);                                                    \
      const float e = __expf(s);                                             \
      p[K] = e; sum += e;                                                    \
      const float2 v01 = __half22float2(*(const __half2*)&kvp[K].y);         \
      const float2 v23 = __half22float2(*(const __half2*)&kvp[K].w);         \
      a0 += e * v01.x; a1 += e * v01.y; a2 += e * v23.x; a3 += e * v23.y;    \
    }
    CSTEP(0)  CSTEP(1)  CSTEP(2)  CSTEP(3)
    CSTEP(4)  CSTEP(5)  CSTEP(6)  CSTEP(7)
    CSTEP(8)  CSTEP(9)  CSTEP(10) CSTEP(11)
    CSTEP(12) CSTEP(13) CSTEP(14) CSTEP(15)
#undef CSTEP

    const float inv = 1.f / sum;

    // centrality: lane d scatters neighbors k=4d..4d+3 (ids = idq.x..w).
    // p[] indices are compile-time; select over runtime d via cndmask.
    const float w0 = (d == 0 ? p[0] : d == 1 ? p[4] : d == 2 ? p[8]  : p[12]) * inv;
    const float w1 = (d == 0 ? p[1] : d == 1 ? p[5] : d == 2 ? p[9]  : p[13]) * inv;
    const float w2 = (d == 0 ? p[2] : d == 1 ? p[6] : d == 2 ? p[10] : p[14]) * inv;
    const float w3 = (d == 0 ? p[3] : d == 1 ? p[7] : d == 2 ? p[11] : p[15]) * inv;
    atomicAdd(&lcent[idq.x], w0);
    atomicAdd(&lcent[idq.y], w1);
    atomicAdd(&lcent[idq.z], w2);
    atomicAdd(&lcent[idq.w], w3);

    // feat write: dims 4d..4d+3 of point n; nt: don't pollute the L2 slice
    float* fb = feat + ((size_t)b * CHAN + g * DIM + 4 * d) * NPTS + n;
    __builtin_nontemporal_store(a0 * inv, fb);
    __builtin_nontemporal_store(a1 * inv, fb + NPTS);
    __builtin_nontemporal_store(a2 * inv, fb + 2 * NPTS);
    __builtin_nontemporal_store(a3 * inv, fb + 3 * NPTS);

    // rotate prefetched state
    n = nn; idq = idqn; qq = qqn;
  }

  __syncthreads();
  // flush private slice to partials (non-atomic, coalesced f4v, streaming)
  f4v* p4 = (f4v*)(part + ((size_t)pair * PCHUNK + chunk) * NPTS);
  #pragma unroll
  for (int i2 = 0; i2 < NPTS / 4 / 1024; ++i2)
    __builtin_nontemporal_store(l4[i2 * 1024 + tid], &p4[i2 * 1024 + tid]);
}

// cent[bg,m] = sum_p part[bg,p,m]; thread per float4 of cent.
__global__ __launch_bounds__(256) void reduce_cent_kernel(
    const float* __restrict__ part, float* __restrict__ cent) {
  const int t = blockIdx.x * 256 + threadIdx.x;  // over 36 * 4096
  const int bg = t >> 12;
  const int m4 = (t & 4095) << 2;
  const f4v* p = (const f4v*)(part + ((size_t)bg * PCHUNK) * NPTS + m4);
  f4v s = (f4v){0.f, 0.f, 0.f, 0.f};
  #pragma unroll
  for (int i = 0; i < PCHUNK; ++i) {
    f4v xv = __builtin_nontemporal_load(&p[(size_t)i * (NPTS / 4)]);
    s += xv;
  }
  *(f4v*)(cent + (size_t)bg * NPTS + m4) = s;
}

extern "C" void kernel_launch(void* const* d_in, const int* in_sizes, int n_in,
                              void* d_out, int out_size, void* d_ws, size_t ws_size,
                              hipStream_t stream) {
  const float* q   = (const float*)d_in[0];   // queryandkey (B,C,N)
  const float* v   = (const float*)d_in[1];   // value (B,C,N)
  const int*   idx = (const int*)d_in[2];     // idx_knn (B,N,K)

  float* feat = (float*)d_out;                       // (B,C,N)
  float* cent = feat + (size_t)BATCH * CHAN * NPTS;  // (B,G,N)

  unsigned int* qvT = (unsigned int*)d_ws;               // (B,N,ROWU) packed
  float* part = (float*)(qvT + (size_t)BATCH * NPTS * ROWU);  // (36,16,N)

  // 1) pack q,v into dim-pair interleaved fp16 rows
  dim3 tg(NPTS / TT, (CHAN + TT - 1) / TT, BATCH);
  pack_qv_kernel<<<tg, 256, 0, stream>>>(q, v, qvT);

  // 2) main fused kernel: 576 blocks x 1024 threads, 64KB LDS, XCD swizzle
  gtl_kernel<<<NPAIR * PCHUNK, 1024, 0, stream>>>(qvT, idx, feat, part);

  // 3) reduce partials -> cent (writes every element; no memset needed)
  reduce_cent_kernel<<<(NPAIR * NPTS / 4) / 256, 256, 0, stream>>>(part, cent);
}

// Round 10
// 225.815 us; speedup vs baseline: 2.5948x; 2.2441x over previous
//
#include <hip/hip_runtime.h>
#include <hip/hip_fp16.h>

// Problem constants (fixed by setup_inputs / GTLModuleV1)
#define BATCH 4
#define CHAN  144
#define NPTS  16384
#define KNN   16
#define GRP   9
#define DIM   16
#define ROWU  (GRP * DIM)        // 144 uint32 per point = 576 B row
#define PCHUNK 21                // chunks per (b,g) pair -> 36*21 = 756 blocks
#define NPAIR (BATCH * GRP)      // 36

#define TT 32

typedef __attribute__((ext_vector_type(2))) _Float16 h2v;
typedef __attribute__((ext_vector_type(4))) float f4v;   // clang vector: nt ops OK
typedef __attribute__((ext_vector_type(4))) int   i4v;   // clang vector: nt ops OK
__device__ __forceinline__ h2v as_h2(unsigned int u) {
  union { unsigned int u; h2v h; } c; c.u = u; return c.h;
}

// DPP helpers: quad_perm ops are VALU (no LDS pipe, ~4cy vs ~40cy bpermute).
template<int J>  // broadcast quad-lane J to all 4 lanes of the quad
__device__ __forceinline__ int ibcast(int v) {
  return __builtin_amdgcn_update_dpp(0, v, (J) * 0x55, 0xF, 0xF, true);
}
template<int C>  // C=0xB1: xor1 swap; C=0x4E: xor2 swap (within quad)
__device__ __forceinline__ float fxor(float x) {
  int r = __builtin_amdgcn_update_dpp(0, __builtin_bit_cast(int, x), C, 0xF, 0xF, true);
  return __builtin_bit_cast(float, r);
}

// (C,N) fp32 q,v -> (N, 144 uints): per group g, uint 2i = h2(k_{2i},k_{2i+1}),
// uint 2i+1 = h2(v_{2i},v_{2i+1}). Each (g,m) slice = 64 B; a uint4 at uint
// offset 16g+4d = dims 4d..4d+3 of key AND val (k01,v01,k23,v23 pattern).
__global__ __launch_bounds__(256) void pack_qv_kernel(
    const float* __restrict__ q, const float* __restrict__ v,
    unsigned int* __restrict__ qvT) {
  __shared__ float tq[TT][TT + 1];
  __shared__ float tv[TT][TT + 1];
  const int b = blockIdx.z;
  const float* qb = q + (size_t)b * CHAN * NPTS;
  const float* vb = v + (size_t)b * CHAN * NPTS;
  unsigned int* out = qvT + (size_t)b * NPTS * ROWU;
  const int n0 = blockIdx.x * TT;
  const int c0 = blockIdx.y * TT;
  const int t = threadIdx.x;

  {  // load both tiles: float4 along n (coalesced)
    const int cl = t >> 3, nq = (t & 7) * 4;
    const int c = c0 + cl;
    if (c < CHAN) {
      const float4 a = *(const float4*)&qb[(size_t)c * NPTS + n0 + nq];
      tq[cl][nq + 0] = a.x; tq[cl][nq + 1] = a.y;
      tq[cl][nq + 2] = a.z; tq[cl][nq + 3] = a.w;
      const float4 w = *(const float4*)&vb[(size_t)c * NPTS + n0 + nq];
      tv[cl][nq + 0] = w.x; tv[cl][nq + 1] = w.y;
      tv[cl][nq + 2] = w.z; tv[cl][nq + 3] = w.w;
    }
  }
  __syncthreads();
  {  // store packed dim-pairs: uint4 along c (coalesced 128B per 8-thr cluster)
    const int nl = t >> 3, cq = (t & 7) * 4;
    const int c = c0 + cq;   // multiple of 4
    if (c < CHAN) {
      const int g = c >> 4, r = c & 15;   // r in {0,4,8,12}
      __half2 k01 = __halves2half2(__float2half_rn(tq[cq + 0][nl]),
                                   __float2half_rn(tq[cq + 1][nl]));
      __half2 v01 = __halves2half2(__float2half_rn(tv[cq + 0][nl]),
                                   __float2half_rn(tv[cq + 1][nl]));
      __half2 k23 = __halves2half2(__float2half_rn(tq[cq + 2][nl]),
                                   __float2half_rn(tq[cq + 3][nl]));
      __half2 v23 = __halves2half2(__float2half_rn(tv[cq + 2][nl]),
                                   __float2half_rn(tv[cq + 3][nl]));
      *(uint4*)&out[(size_t)(n0 + nl) * ROWU + g * 16 + r] =
          make_uint4(*(unsigned int*)&k01, *(unsigned int*)&v01,
                     *(unsigned int*)&k23, *(unsigned int*)&v23);
    }
  }
}

// R5 quad-per-point core (proven 103us): quad = point; ONE uint4 gather per
// (point,neighbor); DPP id-bcast + 2-level DPP butterfly; no-max softmax,
// fused value accumulation; LDS-privatized cent (R8: global atomics resolve
// past the non-coherent XCD L2s -> forbidden).
// R9 lesson: quad core needs >64 VGPR; 1024thr/(1024,8) spilled the burst
// to scratch (WRITE 630MB, 4x slower). 512thr/(512,4) cap=128 is mandatory.
// R10: software-pipelined A/B gather bursts. R5's VGPR=56 proves the 16-deep
// burst never materialized (~3-6 in flight/wave -> ~45 lines/CU by Little's
// law, under MSHR capacity). Split 16 gathers into A[8],B[8]: issue A, issue
// B, consume A WHILE B is in flight, consume B. Peak live = 64(kvp) + ~40
// state < 128 cap. p[16] -> kp[4] (lane keeps only its 4 scatter weights,
// compile-time cndmask select) pays for the second buffer (-12 VGPR).
__global__ __launch_bounds__(512, 4) void gtl_kernel(
    const unsigned int* __restrict__ qvT,  // (B, N, ROWU) packed
    const int*   __restrict__ idx,         // (B, N, K)
    float* __restrict__ feat,              // (B, C, N)
    float* __restrict__ part)              // (NPAIR, PCHUNK, NPTS)
{
  // ---- XCD-partitioned decode: grid 760 = 8*95; even-x XCDs have 95 real
  // blocks, odd-x 94 (+4 dummies). R4-verified bijective decode. ----
  const int i = blockIdx.x;
  const int x = i & 7, sblk = i >> 3;     // sblk in 0..94
  if (sblk >= 94 + ((x & 1) ^ 1)) return; // 4 dummy blocks (odd x, sblk=94)
  int pair, chunk;
  if (sblk < 84) { pair = x + 8 * (sblk / PCHUNK); chunk = sblk % PCHUNK; }
  else           { pair = 32 + (x >> 1); chunk = (sblk - 84) + 11 * (x & 1); }
  const int b = pair / GRP;
  const int g = pair - b * GRP;

  __shared__ float lcent[NPTS];     // 64 KB private cent[b,g,:]
  const int tid = threadIdx.x;

  f4v* l4 = (f4v*)lcent;
  #pragma unroll
  for (int ii = 0; ii < NPTS / 4 / 512; ++ii)
    l4[ii * 512 + tid] = (f4v){0.f, 0.f, 0.f, 0.f};
  __syncthreads();

  // chunk -> contiguous range of 128-point groups (128 groups per pair):
  // 2 chunks of 7 groups + 19 chunks of 6 groups = 128.
  const int ngroups = 6 + (chunk < 2 ? 1 : 0);
  const int gstart  = 6 * chunk + (chunk < 2 ? chunk : 2);

  const int lane = tid & 63;
  const int wv   = tid >> 6;        // 8 waves / block
  const int slot = lane >> 2;       // point within wave [0,16)
  const int d    = lane & 3;        // dim-quad within group [0,4)

  // Uniform (SGPR) byte bases; per-lane 32-bit offsets (qvT slice < 9.4 MB).
  const char* qvb  = (const char*)qvT + (size_t)b * NPTS * (ROWU * 4);
  const char* idxB = (const char*)idx + (size_t)b * NPTS * (KNN * 4);
  const unsigned laneB  = (unsigned)(g * 64 + d * 16);   // g*DIM*4 + 4*d*4
  const unsigned idxoff = (unsigned)(d * 16);

  // ---- prologue: iteration 0's idx quad + q fragment ----
  int n = gstart * 128 + wv * 16 + slot;
  i4v idq = __builtin_nontemporal_load(
      (const i4v*)(idxB + (unsigned)n * 64u + idxoff));   // ids 4d..4d+3
  uint4 qq = *(const uint4*)(qvb + (unsigned)n * (ROWU * 4u) + laneB);

  for (int it = 0; it < ngroups; ++it) {
    const h2v q01 = as_h2(qq.x);
    const h2v q23 = as_h2(qq.z);

    // ---- burst A: neighbors 0..7 (quad-lanes 0,1), 8 uint4 in flight ----
    uint4 kvpA[8];
#define GSTEP(ARR, K)                                                        \
    {                                                                        \
      const int mk = ibcast<((K) >> 2)>(                                     \
          ((K) & 3) == 0 ? idq.x : ((K) & 3) == 1 ? idq.y                    \
                         : ((K) & 3) == 2 ? idq.z : idq.w);                  \
      ARR = *(const uint4*)(qvb + (unsigned)mk * (ROWU * 4u) + laneB);       \
    }
    GSTEP(kvpA[0], 0)  GSTEP(kvpA[1], 1)  GSTEP(kvpA[2], 2)  GSTEP(kvpA[3], 3)
    GSTEP(kvpA[4], 4)  GSTEP(kvpA[5], 5)  GSTEP(kvpA[6], 6)  GSTEP(kvpA[7], 7)
    __builtin_amdgcn_sched_barrier(0);

    // ---- burst B: neighbors 8..15 (quad-lanes 2,3) ----
    uint4 kvpB[8];
    GSTEP(kvpB[0], 8)  GSTEP(kvpB[1], 9)  GSTEP(kvpB[2], 10) GSTEP(kvpB[3], 11)
    GSTEP(kvpB[4], 12) GSTEP(kvpB[5], 13) GSTEP(kvpB[6], 14) GSTEP(kvpB[7], 15)
#undef GSTEP

    // ---- prefetch next iteration's idx quad + q fragment under the flight ----
    const int itn = (it + 1 < ngroups) ? it + 1 : it;   // clamp: no OOB
    const int nn = (gstart + itn) * 128 + wv * 16 + slot;
    const i4v idqn = __builtin_nontemporal_load(
        (const i4v*)(idxB + (unsigned)nn * 64u + idxoff));
    const uint4 qqn = *(const uint4*)(qvb + (unsigned)nn * (ROWU * 4u) + laneB);

    // Pin: all issues above; consumption below. Consuming A only needs
    // vmcnt to drain to B+prefetch depth -> A overlaps B's flight.
    __builtin_amdgcn_sched_barrier(0);

    // ---- consume: score (fdot2 + 2-level DPP butterfly, quad-uniform),
    //      no-max exp, fused value accumulation. kp[j] keeps only this
    //      lane's scatter weights (K = 4d+j), compile-time indices. ----
    float kp[4] = {0.f, 0.f, 0.f, 0.f};
    float sum = 0.f, a0 = 0.f, a1 = 0.f, a2 = 0.f, a3 = 0.f;
#define CSTEP(V, K)                                                          \
    {                                                                        \
      float s = __builtin_amdgcn_fdot2(as_h2((V).x), q01, 0.f, false);       \
      s = __builtin_amdgcn_fdot2(as_h2((V).z), q23, s, false);               \
      s += fxor<0xB1>(s);                                                    \
      s += fxor<0x4E>(s);                                                    \
      const float e = __expf(s);                                             \
      sum += e;                                                              \
      kp[(K) & 3] = (d == ((K) >> 2)) ? e : kp[(K) & 3];                     \
      const float2 v01 = __half22float2(*(const __half2*)&(V).y);            \
      const float2 v23 = __half22float2(*(const __half2*)&(V).w);            \
      a0 += e * v01.x; a1 += e * v01.y; a2 += e * v23.x; a3 += e * v23.y;    \
    }
    CSTEP(kvpA[0], 0)  CSTEP(kvpA[1], 1)  CSTEP(kvpA[2], 2)  CSTEP(kvpA[3], 3)
    CSTEP(kvpA[4], 4)  CSTEP(kvpA[5], 5)  CSTEP(kvpA[6], 6)  CSTEP(kvpA[7], 7)
    CSTEP(kvpB[0], 8)  CSTEP(kvpB[1], 9)  CSTEP(kvpB[2], 10) CSTEP(kvpB[3], 11)
    CSTEP(kvpB[4], 12) CSTEP(kvpB[5], 13) CSTEP(kvpB[6], 14) CSTEP(kvpB[7], 15)
#undef CSTEP

    const float inv = 1.f / sum;

    // centrality: lane d scatters neighbors 4d..4d+3 (ids idq.x..w)
    atomicAdd(&lcent[idq.x], kp[0] * inv);
    atomicAdd(&lcent[idq.y], kp[1] * inv);
    atomicAdd(&lcent[idq.z], kp[2] * inv);
    atomicAdd(&lcent[idq.w], kp[3] * inv);

    // feat write: dims 4d..4d+3 of point n; nt: don't pollute the L2 slice
    float* fb = feat + ((size_t)b * CHAN + g * DIM + 4 * d) * NPTS + n;
    __builtin_nontemporal_store(a0 * inv, fb);
    __builtin_nontemporal_store(a1 * inv, fb + NPTS);
    __builtin_nontemporal_store(a2 * inv, fb + 2 * NPTS);
    __builtin_nontemporal_store(a3 * inv, fb + 3 * NPTS);

    // rotate prefetched state
    n = nn; idq = idqn; qq = qqn;
  }

  __syncthreads();
  // flush private slice to part (non-atomic, coalesced f4v, streaming).
  // Rotation by chunk*512 f4v: the pair's 21 blocks sweep disjoint regions.
  f4v* p4 = (f4v*)(part + ((size_t)pair * PCHUNK + chunk) * NPTS);
  #pragma unroll
  for (int i2 = 0; i2 < NPTS / 4 / 512; ++i2) {
    const int j = (i2 * 512 + tid + chunk * 512) & 4095;
    __builtin_nontemporal_store(l4[j], &p4[j]);
  }
}

// cent[bg,m] = sum_p part[bg,p,m]; thread per float4 of cent.
__global__ __launch_bounds__(256) void reduce_cent_kernel(
    const float* __restrict__ part, float* __restrict__ cent) {
  const int t = blockIdx.x * 256 + threadIdx.x;  // over 36 * 4096
  const int bg = t >> 12;
  const int m4 = (t & 4095) << 2;
  const f4v* p = (const f4v*)(part + ((size_t)bg * PCHUNK) * NPTS + m4);
  f4v s = (f4v){0.f, 0.f, 0.f, 0.f};
  #pragma unroll
  for (int i = 0; i < PCHUNK; ++i) {
    f4v xv = __builtin_nontemporal_load(&p[(size_t)i * (NPTS / 4)]);
    s += xv;
  }
  *(f4v*)(cent + (size_t)bg * NPTS + m4) = s;
}

extern "C" void kernel_launch(void* const* d_in, const int* in_sizes, int n_in,
                              void* d_out, int out_size, void* d_ws, size_t ws_size,
                              hipStream_t stream) {
  const float* q   = (const float*)d_in[0];   // queryandkey (B,C,N)
  const float* v   = (const float*)d_in[1];   // value (B,C,N)
  const int*   idx = (const int*)d_in[2];     // idx_knn (B,N,K)

  float* feat = (float*)d_out;                       // (B,C,N)
  float* cent = feat + (size_t)BATCH * CHAN * NPTS;  // (B,G,N)

  unsigned int* qvT = (unsigned int*)d_ws;               // (B,N,ROWU) packed
  float* part = (float*)(qvT + (size_t)BATCH * NPTS * ROWU);  // (36,21,N)

  // 1) pack q,v into dim-pair interleaved fp16 rows
  dim3 tg(NPTS / TT, (CHAN + TT - 1) / TT, BATCH);
  pack_qv_kernel<<<tg, 256, 0, stream>>>(q, v, qvT);

  // 2) main fused kernel: 760 blocks (756 real) x 512 threads, 64KB LDS,
  //    XCD swizzle; A/B pipelined gather bursts
  gtl_kernel<<<760, 512, 0, stream>>>(qvT, idx, feat, part);

  // 3) reduce partials -> cent (writes every element; no memset needed)
  reduce_cent_kernel<<<(NPAIR * NPTS / 4) / 256, 256, 0, stream>>>(part, cent);
}

// Round 11
// 210.453 us; speedup vs baseline: 2.7842x; 1.0730x over previous
//
#include <hip/hip_runtime.h>
#include <hip/hip_fp16.h>

// Problem constants (fixed by setup_inputs / GTLModuleV1)
#define BATCH 4
#define CHAN  144
#define NPTS  16384
#define KNN   16
#define GRP   9
#define DIM   16
#define ROWU  (GRP * DIM)        // 144 uint32 per point = 576 B row
#define PCHUNK 21                // chunks per (b,g) pair -> 36*21 = 756 blocks
#define NPAIR (BATCH * GRP)      // 36

#define TT 32

typedef __attribute__((ext_vector_type(2))) _Float16 h2v;
typedef __attribute__((ext_vector_type(4))) float    f4v;
typedef __attribute__((ext_vector_type(4))) int      i4v;
typedef __attribute__((ext_vector_type(4))) unsigned u4v;
__device__ __forceinline__ h2v as_h2(unsigned int u) {
  union { unsigned int u; h2v h; } c; c.u = u; return c.h;
}
__device__ __forceinline__ float2 h2f(unsigned u) {
  union { unsigned u; __half2 h; } c; c.u = u;
  return __half22float2(c.h);
}

// DPP helpers: quad_perm ops are VALU (no LDS pipe, ~4cy vs ~40cy bpermute).
template<int J>  // broadcast quad-lane J to all 4 lanes of the quad
__device__ __forceinline__ int ibcast(int v) {
  return __builtin_amdgcn_update_dpp(0, v, (J) * 0x55, 0xF, 0xF, true);
}
template<int C>  // C=0xB1: xor1 swap; C=0x4E: xor2 swap (within quad)
__device__ __forceinline__ float fxor(float x) {
  int r = __builtin_amdgcn_update_dpp(0, __builtin_bit_cast(int, x), C, 0xF, 0xF, true);
  return __builtin_bit_cast(float, r);
}

// (C,N) fp32 q,v -> (N, 144 uints): per group g, uint 2i = h2(k_{2i},k_{2i+1}),
// uint 2i+1 = h2(v_{2i},v_{2i+1}). Each (g,m) slice = 64 B; a uint4 at uint
// offset 16g+4d = dims 4d..4d+3 of key AND val (k01,v01,k23,v23 pattern).
__global__ __launch_bounds__(256) void pack_qv_kernel(
    const float* __restrict__ q, const float* __restrict__ v,
    unsigned int* __restrict__ qvT) {
  __shared__ float tq[TT][TT + 1];
  __shared__ float tv[TT][TT + 1];
  const int b = blockIdx.z;
  const float* qb = q + (size_t)b * CHAN * NPTS;
  const float* vb = v + (size_t)b * CHAN * NPTS;
  unsigned int* out = qvT + (size_t)b * NPTS * ROWU;
  const int n0 = blockIdx.x * TT;
  const int c0 = blockIdx.y * TT;
  const int t = threadIdx.x;

  {  // load both tiles: float4 along n (coalesced)
    const int cl = t >> 3, nq = (t & 7) * 4;
    const int c = c0 + cl;
    if (c < CHAN) {
      const float4 a = *(const float4*)&qb[(size_t)c * NPTS + n0 + nq];
      tq[cl][nq + 0] = a.x; tq[cl][nq + 1] = a.y;
      tq[cl][nq + 2] = a.z; tq[cl][nq + 3] = a.w;
      const float4 w = *(const float4*)&vb[(size_t)c * NPTS + n0 + nq];
      tv[cl][nq + 0] = w.x; tv[cl][nq + 1] = w.y;
      tv[cl][nq + 2] = w.z; tv[cl][nq + 3] = w.w;
    }
  }
  __syncthreads();
  {  // store packed dim-pairs: uint4 along c (coalesced 128B per 8-thr cluster)
    const int nl = t >> 3, cq = (t & 7) * 4;
    const int c = c0 + cq;   // multiple of 4
    if (c < CHAN) {
      const int g = c >> 4, r = c & 15;   // r in {0,4,8,12}
      __half2 k01 = __halves2half2(__float2half_rn(tq[cq + 0][nl]),
                                   __float2half_rn(tq[cq + 1][nl]));
      __half2 v01 = __halves2half2(__float2half_rn(tv[cq + 0][nl]),
                                   __float2half_rn(tv[cq + 1][nl]));
      __half2 k23 = __halves2half2(__float2half_rn(tq[cq + 2][nl]),
                                   __float2half_rn(tq[cq + 3][nl]));
      __half2 v23 = __halves2half2(__float2half_rn(tv[cq + 2][nl]),
                                   __float2half_rn(tv[cq + 3][nl]));
      *(uint4*)&out[(size_t)(n0 + nl) * ROWU + g * 16 + r] =
          make_uint4(*(unsigned int*)&k01, *(unsigned int*)&v01,
                     *(unsigned int*)&k23, *(unsigned int*)&v23);
    }
  }
}

// R5 quad-per-point core (103us): quad = point; ONE uint4 gather per
// (point,neighbor); DPP id-bcast + 2-level DPP butterfly; no-max softmax,
// fused value accumulation; LDS-privatized cent (R8: global atomics bypass
// the non-coherent XCD L2s -> forbidden). 512thr/(512,4) mandatory (R9:
// 1024thr spilled the burst, 4x slower).
// R11: the gather burst is forced with INLINE ASM. R1/R5/R10 all nulled
// with VGPR=56: sched_barrier is IntrNoMem, so IR passes sink the loads to
// their uses and the scheduler's pressure heuristic keeps ~4 in flight
// (~50 lines/CU by Little's law at ~300cy L2 latency = the measured 0.16
// lines/cy). asm volatile global_load_dwordx4 (SGPR base + 32b voffset)
// cannot be sunk. Manual counted waits, "memory"-clobbered so the feat
// stores stay pinned in their window and counts stay exact:
//   issue G0..G15, P_idx, P_q
//   vmcnt(10): G0..7 done  -> consume A (B + prefetch still in flight)
//   vmcnt(2):  G8..15 done -> consume B (prefetch still in flight)
//   feat stores (4) -> vmcnt(4): prefetch landed, stores may linger
// sched_barrier(0) after each wait (compiler hoists reg-only ops past asm
// waitcnt otherwise). Final vmcnt(0) after the loop: no in-flight load may
// clobber a reused register.
__global__ __launch_bounds__(512, 4) void gtl_kernel(
    const unsigned int* __restrict__ qvT,  // (B, N, ROWU) packed
    const int*   __restrict__ idx,         // (B, N, K)
    float* __restrict__ feat,              // (B, C, N)
    float* __restrict__ part)              // (NPAIR, PCHUNK, NPTS)
{
  // ---- XCD-partitioned decode: grid 760 = 8*95; even-x XCDs have 95 real
  // blocks, odd-x 94 (+4 dummies). R4-verified bijective decode. ----
  const int i = blockIdx.x;
  const int x = i & 7, sblk = i >> 3;     // sblk in 0..94
  if (sblk >= 94 + ((x & 1) ^ 1)) return; // 4 dummy blocks (odd x, sblk=94)
  int pair, chunk;
  if (sblk < 84) { pair = x + 8 * (sblk / PCHUNK); chunk = sblk % PCHUNK; }
  else           { pair = 32 + (x >> 1); chunk = (sblk - 84) + 11 * (x & 1); }
  const int b = pair / GRP;
  const int g = pair - b * GRP;

  __shared__ float lcent[NPTS];     // 64 KB private cent[b,g,:]
  const int tid = threadIdx.x;

  f4v* l4 = (f4v*)lcent;
  #pragma unroll
  for (int ii = 0; ii < NPTS / 4 / 512; ++ii)
    l4[ii * 512 + tid] = (f4v){0.f, 0.f, 0.f, 0.f};
  __syncthreads();

  // chunk -> contiguous range of 128-point groups (128 groups per pair):
  // 2 chunks of 7 groups + 19 chunks of 6 groups = 128.
  const int ngroups = 6 + (chunk < 2 ? 1 : 0);
  const int gstart  = 6 * chunk + (chunk < 2 ? chunk : 2);

  const int lane = tid & 63;
  const int wv   = tid >> 6;        // 8 waves / block
  const int slot = lane >> 2;       // point within wave [0,16)
  const int d    = lane & 3;        // dim-quad within group [0,4)

  // Uniform (SGPR) bases; per-lane 32-bit voffsets (qvT slice < 9.4 MB).
  const char* qvb  = (const char*)qvT + (size_t)b * NPTS * (ROWU * 4);
  const char* idxB = (const char*)idx + (size_t)b * NPTS * (KNN * 4);
  const unsigned laneB  = (unsigned)(g * 64 + d * 16);   // g*DIM*4 + 4*d*4
  const unsigned idxoff = (unsigned)(d * 16);

  // ---- prologue: iteration 0's idx quad + q fragment (asm, then drain) ----
  int n = gstart * 128 + wv * 16 + slot;
  i4v idq; u4v qq;
  asm volatile("global_load_dwordx4 %0, %1, %2"
               : "=v"(idq) : "v"((unsigned)n * 64u + idxoff), "s"(idxB));
  asm volatile("global_load_dwordx4 %0, %1, %2"
               : "=v"(qq) : "v"((unsigned)n * (ROWU * 4u) + laneB), "s"(qvb));
  asm volatile("s_waitcnt vmcnt(0)" ::: "memory");
  __builtin_amdgcn_sched_barrier(0);

  for (int it = 0; it < ngroups; ++it) {
    const h2v q01 = as_h2(qq.x);
    const h2v q23 = as_h2(qq.z);

    // ---- forced burst: 16 uint4 gathers issued back-to-back ----
    u4v kvA[8], kvB[8];
#define GISS(DST, K)                                                         \
    {                                                                        \
      const int mk = ibcast<((K) >> 2)>(                                     \
          ((K) & 3) == 0 ? idq.x : ((K) & 3) == 1 ? idq.y                    \
                         : ((K) & 3) == 2 ? idq.z : idq.w);                  \
      const unsigned vo = (unsigned)mk * (ROWU * 4u) + laneB;                \
      asm volatile("global_load_dwordx4 %0, %1, %2"                          \
                   : "=v"(DST) : "v"(vo), "s"(qvb));                         \
    }
    GISS(kvA[0], 0)  GISS(kvA[1], 1)  GISS(kvA[2], 2)  GISS(kvA[3], 3)
    GISS(kvA[4], 4)  GISS(kvA[5], 5)  GISS(kvA[6], 6)  GISS(kvA[7], 7)
    GISS(kvB[0], 8)  GISS(kvB[1], 9)  GISS(kvB[2], 10) GISS(kvB[3], 11)
    GISS(kvB[4], 12) GISS(kvB[5], 13) GISS(kvB[6], 14) GISS(kvB[7], 15)
#undef GISS

    // ---- prefetch next iteration's idx quad + q fragment (in flight) ----
    const int itn = (it + 1 < ngroups) ? it + 1 : it;   // clamp: no OOB
    const int nn = (gstart + itn) * 128 + wv * 16 + slot;
    i4v idqn; u4v qqn;
    asm volatile("global_load_dwordx4 %0, %1, %2"
                 : "=v"(idqn) : "v"((unsigned)nn * 64u + idxoff), "s"(idxB));
    asm volatile("global_load_dwordx4 %0, %1, %2"
                 : "=v"(qqn) : "v"((unsigned)nn * (ROWU * 4u) + laneB), "s"(qvb));

    // ---- consume A while B + prefetch are still in flight ----
    asm volatile("s_waitcnt vmcnt(10)" ::: "memory");
    __builtin_amdgcn_sched_barrier(0);

    float kp[4] = {0.f, 0.f, 0.f, 0.f};
    float sum = 0.f, a0 = 0.f, a1 = 0.f, a2 = 0.f, a3 = 0.f;
#define CSTEP(V, K)                                                          \
    {                                                                        \
      float s = __builtin_amdgcn_fdot2(as_h2((V).x), q01, 0.f, false);       \
      s = __builtin_amdgcn_fdot2(as_h2((V).z), q23, s, false);               \
      s += fxor<0xB1>(s);                                                    \
      s += fxor<0x4E>(s);                                                    \
      const float e = __expf(s);                                             \
      sum += e;                                                              \
      kp[(K) & 3] = (d == ((K) >> 2)) ? e : kp[(K) & 3];                     \
      const float2 v01 = h2f((V).y);                                         \
      const float2 v23 = h2f((V).w);                                         \
      a0 += e * v01.x; a1 += e * v01.y; a2 += e * v23.x; a3 += e * v23.y;    \
    }
    CSTEP(kvA[0], 0)  CSTEP(kvA[1], 1)  CSTEP(kvA[2], 2)  CSTEP(kvA[3], 3)
    CSTEP(kvA[4], 4)  CSTEP(kvA[5], 5)  CSTEP(kvA[6], 6)  CSTEP(kvA[7], 7)

    // ---- consume B (prefetch still in flight) ----
    asm volatile("s_waitcnt vmcnt(2)" ::: "memory");
    __builtin_amdgcn_sched_barrier(0);
    CSTEP(kvB[0], 8)  CSTEP(kvB[1], 9)  CSTEP(kvB[2], 10) CSTEP(kvB[3], 11)
    CSTEP(kvB[4], 12) CSTEP(kvB[5], 13) CSTEP(kvB[6], 14) CSTEP(kvB[7], 15)
#undef CSTEP

    const float inv = 1.f / sum;

    // centrality: lane d scatters neighbors 4d..4d+3 (ids idq.x..w)
    atomicAdd(&lcent[idq.x], kp[0] * inv);
    atomicAdd(&lcent[idq.y], kp[1] * inv);
    atomicAdd(&lcent[idq.z], kp[2] * inv);
    atomicAdd(&lcent[idq.w], kp[3] * inv);

    // feat write: dims 4d..4d+3 of point n; nt: don't pollute the L2 slice
    float* fb = feat + ((size_t)b * CHAN + g * DIM + 4 * d) * NPTS + n;
    __builtin_nontemporal_store(a0 * inv, fb);
    __builtin_nontemporal_store(a1 * inv, fb + NPTS);
    __builtin_nontemporal_store(a2 * inv, fb + 2 * NPTS);
    __builtin_nontemporal_store(a3 * inv, fb + 3 * NPTS);

    // ---- land the prefetch (stores may linger: 4 youngest) ----
    asm volatile("s_waitcnt vmcnt(4)" ::: "memory");
    __builtin_amdgcn_sched_barrier(0);

    // rotate prefetched state
    n = nn; idq = idqn; qq = qqn;
  }
  // drain everything before registers are reused by the flush
  asm volatile("s_waitcnt vmcnt(0)" ::: "memory");
  __builtin_amdgcn_sched_barrier(0);

  __syncthreads();
  // flush private slice to part (non-atomic, coalesced f4v, streaming).
  // Rotation by chunk*512 f4v: the pair's 21 blocks sweep disjoint regions.
  f4v* p4 = (f4v*)(part + ((size_t)pair * PCHUNK + chunk) * NPTS);
  #pragma unroll
  for (int i2 = 0; i2 < NPTS / 4 / 512; ++i2) {
    const int j = (i2 * 512 + tid + chunk * 512) & 4095;
    __builtin_nontemporal_store(l4[j], &p4[j]);
  }
}

// cent[bg,m] = sum_p part[bg,p,m]; thread per float4 of cent.
__global__ __launch_bounds__(256) void reduce_cent_kernel(
    const float* __restrict__ part, float* __restrict__ cent) {
  const int t = blockIdx.x * 256 + threadIdx.x;  // over 36 * 4096
  const int bg = t >> 12;
  const int m4 = (t & 4095) << 2;
  const f4v* p = (const f4v*)(part + ((size_t)bg * PCHUNK) * NPTS + m4);
  f4v s = (f4v){0.f, 0.f, 0.f, 0.f};
  #pragma unroll
  for (int i = 0; i < PCHUNK; ++i) {
    f4v xv = __builtin_nontemporal_load(&p[(size_t)i * (NPTS / 4)]);
    s += xv;
  }
  *(f4v*)(cent + (size_t)bg * NPTS + m4) = s;
}

extern "C" void kernel_launch(void* const* d_in, const int* in_sizes, int n_in,
                              void* d_out, int out_size, void* d_ws, size_t ws_size,
                              hipStream_t stream) {
  const float* q   = (const float*)d_in[0];   // queryandkey (B,C,N)
  const float* v   = (const float*)d_in[1];   // value (B,C,N)
  const int*   idx = (const int*)d_in[2];     // idx_knn (B,N,K)

  float* feat = (float*)d_out;                       // (B,C,N)
  float* cent = feat + (size_t)BATCH * CHAN * NPTS;  // (B,G,N)

  unsigned int* qvT = (unsigned int*)d_ws;               // (B,N,ROWU) packed
  float* part = (float*)(qvT + (size_t)BATCH * NPTS * ROWU);  // (36,21,N)

  // 1) pack q,v into dim-pair interleaved fp16 rows
  dim3 tg(NPTS / TT, (CHAN + TT - 1) / TT, BATCH);
  pack_qv_kernel<<<tg, 256, 0, stream>>>(q, v, qvT);

  // 2) main fused kernel: 760 blocks (756 real) x 512 threads, 64KB LDS,
  //    XCD swizzle; inline-asm forced 16-deep gather bursts
  gtl_kernel<<<760, 512, 0, stream>>>(qvT, idx, feat, part);

  // 3) reduce partials -> cent (writes every element; no memset needed)
  reduce_cent_kernel<<<(NPAIR * NPTS / 4) / 256, 256, 0, stream>>>(part, cent);
}

// Round 12
// 210.163 us; speedup vs baseline: 2.7881x; 1.0014x over previous
//
#include <hip/hip_runtime.h>
#include <hip/hip_fp16.h>

// Problem constants (fixed by setup_inputs / GTLModuleV1)
#define BATCH 4
#define CHAN  144
#define NPTS  16384
#define KNN   16
#define GRP   9
#define DIM   16
#define ROWU2 160                // padded row: 144 data uints + 16 pad = 640 B
#define PCHA  16                 // chunks per group-pair unit (16 PU -> 256 blocks)
#define PCHB  32                 // chunks per batch for the g=8 kernel (128 blocks)
#define NPAIR (BATCH * GRP)      // 36

#define TT 32

typedef __attribute__((ext_vector_type(2))) _Float16 h2v;
typedef __attribute__((ext_vector_type(4))) float    f4v;
typedef __attribute__((ext_vector_type(4))) int      i4v;
typedef __attribute__((ext_vector_type(4))) unsigned u4v;
__device__ __forceinline__ h2v as_h2(unsigned int u) {
  union { unsigned int u; h2v h; } c; c.u = u; return c.h;
}
__device__ __forceinline__ float2 h2f(unsigned u) {
  union { unsigned u; __half2 h; } c; c.u = u;
  return __half22float2(c.h);
}

// DPP helpers (quad_perm = VALU, no LDS pipe).
template<int J>
__device__ __forceinline__ int ibcast(int v) {
  return __builtin_amdgcn_update_dpp(0, v, (J) * 0x55, 0xF, 0xF, true);
}
template<int C>
__device__ __forceinline__ float fxor(float x) {
  int r = __builtin_amdgcn_update_dpp(0, __builtin_bit_cast(int, x), C, 0xF, 0xF, true);
  return __builtin_bit_cast(float, r);
}

// (C,N) fp32 q,v -> (N, 160 uints, 640B rows, 128B-aligned group-pairs):
// uint offset for channel c = (c>>4)*16 + (c&15) = c; uints 144..159 pad
// (never read: pairs j<4 read [j*32, j*32+32), g=8 reads [128,144)).
__global__ __launch_bounds__(256) void pack_qv_kernel(
    const float* __restrict__ q, const float* __restrict__ v,
    unsigned int* __restrict__ qvT) {
  __shared__ float tq[TT][TT + 1];
  __shared__ float tv[TT][TT + 1];
  const int b = blockIdx.z;
  const float* qb = q + (size_t)b * CHAN * NPTS;
  const float* vb = v + (size_t)b * CHAN * NPTS;
  unsigned int* out = qvT + (size_t)b * NPTS * ROWU2;
  const int n0 = blockIdx.x * TT;
  const int c0 = blockIdx.y * TT;
  const int t = threadIdx.x;

  {  // load both tiles: float4 along n (coalesced)
    const int cl = t >> 3, nq = (t & 7) * 4;
    const int c = c0 + cl;
    if (c < CHAN) {
      const float4 a = *(const float4*)&qb[(size_t)c * NPTS + n0 + nq];
      tq[cl][nq + 0] = a.x; tq[cl][nq + 1] = a.y;
      tq[cl][nq + 2] = a.z; tq[cl][nq + 3] = a.w;
      const float4 w = *(const float4*)&vb[(size_t)c * NPTS + n0 + nq];
      tv[cl][nq + 0] = w.x; tv[cl][nq + 1] = w.y;
      tv[cl][nq + 2] = w.z; tv[cl][nq + 3] = w.w;
    }
  }
  __syncthreads();
  {  // store packed dim-pairs: uint4 along c
    const int nl = t >> 3, cq = (t & 7) * 4;
    const int c = c0 + cq;   // multiple of 4
    if (c < CHAN) {
      __half2 k01 = __halves2half2(__float2half_rn(tq[cq + 0][nl]),
                                   __float2half_rn(tq[cq + 1][nl]));
      __half2 v01 = __halves2half2(__float2half_rn(tv[cq + 0][nl]),
                                   __float2half_rn(tv[cq + 1][nl]));
      __half2 k23 = __halves2half2(__float2half_rn(tq[cq + 2][nl]),
                                   __float2half_rn(tq[cq + 3][nl]));
      __half2 v23 = __halves2half2(__float2half_rn(tv[cq + 2][nl]),
                                   __float2half_rn(tv[cq + 3][nl]));
      *(uint4*)&out[(size_t)(n0 + nl) * ROWU2 + c] =
          make_uint4(*(unsigned int*)&k01, *(unsigned int*)&v01,
                     *(unsigned int*)&k23, *(unsigned int*)&v23);
    }
  }
}

// Kernel A: group-PAIR blocks. Wave = 8 points x 8 lanes; 8-lane group =
// {gh=0 quad (group 2j), gh=1 quad (group 2j+1)} reading ONE 128B-aligned
// contiguous segment per (point,neighbor) -> transactions per delivered
// byte halve IF the TCP fill granule is 128B (the round's hypothesis).
// R11's forced-asm 18-deep pipeline retained verbatim. 16 PU (4b x 4j) x
// 16 chunks = 256 blocks = exactly 1 block/CU (128KB LDS), perfect balance.
__global__ __launch_bounds__(512, 4) void gtl_pair_kernel(
    const unsigned int* __restrict__ qvT,  // (B, N, ROWU2)
    const int*   __restrict__ idx,         // (B, N, K)
    float* __restrict__ feat,              // (B, C, N)
    float* __restrict__ partA)             // (16, PCHA, 2, NPTS)
{
  // grid 256 = 8 XCDs x 32: PU = x + 8*(sblk>>4), chunk = sblk&15.
  const int i = blockIdx.x;
  const int x = i & 7, sblk = i >> 3;
  const int PU = x + 8 * (sblk >> 4);
  const int chunk = sblk & 15;
  const int b = PU >> 2, j = PU & 3;       // groups 2j, 2j+1

  extern __shared__ float lcent[];         // 2 * NPTS floats = 128 KB
  const int tid = threadIdx.x;

  f4v* l4 = (f4v*)lcent;
  #pragma unroll
  for (int ii = 0; ii < 2 * NPTS / 4 / 512; ++ii)
    l4[ii * 512 + tid] = (f4v){0.f, 0.f, 0.f, 0.f};
  __syncthreads();

  const int lane = tid & 63;
  const int wv   = tid >> 6;        // 8 waves
  const int slot = lane >> 3;       // point within wave [0,8)
  const int e    = lane & 7;        // 16B-slot within 128B pair-segment
  const int gh   = e >> 2;          // which group of the pair
  const int d    = e & 3;           // dim-quad within group

  const char* qvb  = (const char*)qvT + (size_t)b * NPTS * (ROWU2 * 4);
  const char* idxB = (const char*)idx + (size_t)b * NPTS * (KNN * 4);
  const unsigned laneB  = (unsigned)(j * 128 + e * 16);
  const unsigned idxoff = (unsigned)(d * 16);

  // prologue: iteration 0's idx quad + q fragment
  int n = chunk * 1024 + wv * 8 + slot;
  i4v idq; u4v qq;
  asm volatile("global_load_dwordx4 %0, %1, %2"
               : "=v"(idq) : "v"((unsigned)n * 64u + idxoff), "s"(idxB));
  asm volatile("global_load_dwordx4 %0, %1, %2"
               : "=v"(qq) : "v"((unsigned)n * (ROWU2 * 4u) + laneB), "s"(qvb));
  asm volatile("s_waitcnt vmcnt(0)" ::: "memory");
  __builtin_amdgcn_sched_barrier(0);

  for (int it = 0; it < 16; ++it) {
    const h2v q01 = as_h2(qq.x);
    const h2v q23 = as_h2(qq.z);

    // forced burst: 16 gathers; per instruction each 8-lane group reads one
    // 128B-aligned segment (row stride 640 = 5*128; j*128 aligned).
    u4v kvA[8], kvB[8];
#define GISS(DST, K)                                                         \
    {                                                                        \
      const int mk = ibcast<((K) >> 2)>(                                     \
          ((K) & 3) == 0 ? idq.x : ((K) & 3) == 1 ? idq.y                    \
                         : ((K) & 3) == 2 ? idq.z : idq.w);                  \
      const unsigned vo = (unsigned)mk * (ROWU2 * 4u) + laneB;               \
      asm volatile("global_load_dwordx4 %0, %1, %2"                          \
                   : "=v"(DST) : "v"(vo), "s"(qvb));                         \
    }
    GISS(kvA[0], 0)  GISS(kvA[1], 1)  GISS(kvA[2], 2)  GISS(kvA[3], 3)
    GISS(kvA[4], 4)  GISS(kvA[5], 5)  GISS(kvA[6], 6)  GISS(kvA[7], 7)
    GISS(kvB[0], 8)  GISS(kvB[1], 9)  GISS(kvB[2], 10) GISS(kvB[3], 11)
    GISS(kvB[4], 12) GISS(kvB[5], 13) GISS(kvB[6], 14) GISS(kvB[7], 15)
#undef GISS

    // prefetch next iteration's idx + q (in flight)
    const int itn = (it + 1 < 16) ? it + 1 : it;
    const int nn = chunk * 1024 + itn * 64 + wv * 8 + slot;
    i4v idqn; u4v qqn;
    asm volatile("global_load_dwordx4 %0, %1, %2"
                 : "=v"(idqn) : "v"((unsigned)nn * 64u + idxoff), "s"(idxB));
    asm volatile("global_load_dwordx4 %0, %1, %2"
                 : "=v"(qqn) : "v"((unsigned)nn * (ROWU2 * 4u) + laneB), "s"(qvb));

    // consume A while B + prefetch in flight
    asm volatile("s_waitcnt vmcnt(10)" ::: "memory");
    __builtin_amdgcn_sched_barrier(0);

    float kp[4] = {0.f, 0.f, 0.f, 0.f};
    float sum = 0.f, a0 = 0.f, a1 = 0.f, a2 = 0.f, a3 = 0.f;
#define CSTEP(V, K)                                                          \
    {                                                                        \
      float s = __builtin_amdgcn_fdot2(as_h2((V).x), q01, 0.f, false);       \
      s = __builtin_amdgcn_fdot2(as_h2((V).z), q23, s, false);               \
      s += fxor<0xB1>(s);                                                    \
      s += fxor<0x4E>(s);                                                    \
      const float e2 = __expf(s);                                            \
      sum += e2;                                                             \
      kp[(K) & 3] = (d == ((K) >> 2)) ? e2 : kp[(K) & 3];                    \
      const float2 v01 = h2f((V).y);                                         \
      const float2 v23 = h2f((V).w);                                         \
      a0 += e2 * v01.x; a1 += e2 * v01.y; a2 += e2 * v23.x; a3 += e2 * v23.y;\
    }
    CSTEP(kvA[0], 0)  CSTEP(kvA[1], 1)  CSTEP(kvA[2], 2)  CSTEP(kvA[3], 3)
    CSTEP(kvA[4], 4)  CSTEP(kvA[5], 5)  CSTEP(kvA[6], 6)  CSTEP(kvA[7], 7)

    asm volatile("s_waitcnt vmcnt(2)" ::: "memory");
    __builtin_amdgcn_sched_barrier(0);
    CSTEP(kvB[0], 8)  CSTEP(kvB[1], 9)  CSTEP(kvB[2], 10) CSTEP(kvB[3], 11)
    CSTEP(kvB[4], 12) CSTEP(kvB[5], 13) CSTEP(kvB[6], 14) CSTEP(kvB[7], 15)
#undef CSTEP

    const float inv = 1.f / sum;

    // centrality: into this block's slice for group gh
    float* lc = lcent + gh * NPTS;
    atomicAdd(&lc[idq.x], kp[0] * inv);
    atomicAdd(&lc[idq.y], kp[1] * inv);
    atomicAdd(&lc[idq.z], kp[2] * inv);
    atomicAdd(&lc[idq.w], kp[3] * inv);

    // feat: group g = 2j+gh (always < 8), dims 4d..4d+3 of point n
    float* fb = feat + ((size_t)b * CHAN + (2 * j + gh) * DIM + 4 * d) * NPTS + n;
    __builtin_nontemporal_store(a0 * inv, fb);
    __builtin_nontemporal_store(a1 * inv, fb + NPTS);
    __builtin_nontemporal_store(a2 * inv, fb + 2 * NPTS);
    __builtin_nontemporal_store(a3 * inv, fb + 3 * NPTS);

    asm volatile("s_waitcnt vmcnt(4)" ::: "memory");
    __builtin_amdgcn_sched_barrier(0);
    n = nn; idq = idqn; qq = qqn;
  }
  asm volatile("s_waitcnt vmcnt(0)" ::: "memory");
  __builtin_amdgcn_sched_barrier(0);

  __syncthreads();
  // flush both slices (rotated so the PU's 16 blocks sweep disjoint regions)
  f4v* p4 = (f4v*)(partA + ((size_t)(PU * PCHA + chunk) * 2) * NPTS);
  #pragma unroll
  for (int i2 = 0; i2 < 2 * NPTS / 4 / 512; ++i2) {
    const int j2 = (i2 * 512 + tid + chunk * 512) & 8191;
    __builtin_nontemporal_store(l4[j2], &p4[j2]);
  }
}

// Kernel B: group 8 via the proven R11 64B path (row stride 640).
// 4 batches x 32 chunks = 128 blocks, 64KB LDS.
__global__ __launch_bounds__(512, 4) void gtl_g8_kernel(
    const unsigned int* __restrict__ qvT,
    const int*   __restrict__ idx,
    float* __restrict__ feat,
    float* __restrict__ partB)             // (4, PCHB, NPTS)
{
  // grid 128 = 8 XCDs x 16: b = x>>1, chunk = sblk + 16*(x&1).
  const int i = blockIdx.x;
  const int x = i & 7, sblk = i >> 3;
  const int b = x >> 1;
  const int chunk = sblk + 16 * (x & 1);

  __shared__ float lcent[NPTS];
  const int tid = threadIdx.x;
  f4v* l4 = (f4v*)lcent;
  #pragma unroll
  for (int ii = 0; ii < NPTS / 4 / 512; ++ii)
    l4[ii * 512 + tid] = (f4v){0.f, 0.f, 0.f, 0.f};
  __syncthreads();

  const int NG = 4;                        // 4 groups of 128 points
  const int gstart = chunk * NG;

  const int lane = tid & 63;
  const int wv   = tid >> 6;
  const int slot = lane >> 2;              // 16 points / wave
  const int d    = lane & 3;

  const char* qvb  = (const char*)qvT + (size_t)b * NPTS * (ROWU2 * 4);
  const char* idxB = (const char*)idx + (size_t)b * NPTS * (KNN * 4);
  const unsigned laneB  = (unsigned)(8 * 64 + d * 16);   // group 8 slice
  const unsigned idxoff = (unsigned)(d * 16);

  int n = gstart * 128 + wv * 16 + slot;
  i4v idq; u4v qq;
  asm volatile("global_load_dwordx4 %0, %1, %2"
               : "=v"(idq) : "v"((unsigned)n * 64u + idxoff), "s"(idxB));
  asm volatile("global_load_dwordx4 %0, %1, %2"
               : "=v"(qq) : "v"((unsigned)n * (ROWU2 * 4u) + laneB), "s"(qvb));
  asm volatile("s_waitcnt vmcnt(0)" ::: "memory");
  __builtin_amdgcn_sched_barrier(0);

  for (int it = 0; it < NG; ++it) {
    const h2v q01 = as_h2(qq.x);
    const h2v q23 = as_h2(qq.z);

    u4v kvA[8], kvB[8];
#define GISS(DST, K)                                                         \
    {                                                                        \
      const int mk = ibcast<((K) >> 2)>(                                     \
          ((K) & 3) == 0 ? idq.x : ((K) & 3) == 1 ? idq.y                    \
                         : ((K) & 3) == 2 ? idq.z : idq.w);                  \
      const unsigned vo = (unsigned)mk * (ROWU2 * 4u) + laneB;               \
      asm volatile("global_load_dwordx4 %0, %1, %2"                          \
                   : "=v"(DST) : "v"(vo), "s"(qvb));                         \
    }
    GISS(kvA[0], 0)  GISS(kvA[1], 1)  GISS(kvA[2], 2)  GISS(kvA[3], 3)
    GISS(kvA[4], 4)  GISS(kvA[5], 5)  GISS(kvA[6], 6)  GISS(kvA[7], 7)
    GISS(kvB[0], 8)  GISS(kvB[1], 9)  GISS(kvB[2], 10) GISS(kvB[3], 11)
    GISS(kvB[4], 12) GISS(kvB[5], 13) GISS(kvB[6], 14) GISS(kvB[7], 15)
#undef GISS

    const int itn = (it + 1 < NG) ? it + 1 : it;
    const int nn = (gstart + itn) * 128 + wv * 16 + slot;
    i4v idqn; u4v qqn;
    asm volatile("global_load_dwordx4 %0, %1, %2"
                 : "=v"(idqn) : "v"((unsigned)nn * 64u + idxoff), "s"(idxB));
    asm volatile("global_load_dwordx4 %0, %1, %2"
                 : "=v"(qqn) : "v"((unsigned)nn * (ROWU2 * 4u) + laneB), "s"(qvb));

    asm volatile("s_waitcnt vmcnt(10)" ::: "memory");
    __builtin_amdgcn_sched_barrier(0);

    float kp[4] = {0.f, 0.f, 0.f, 0.f};
    float sum = 0.f, a0 = 0.f, a1 = 0.f, a2 = 0.f, a3 = 0.f;
#define CSTEP(V, K)                                                          \
    {                                                                        \
      float s = __builtin_amdgcn_fdot2(as_h2((V).x), q01, 0.f, false);       \
      s = __builtin_amdgcn_fdot2(as_h2((V).z), q23, s, false);               \
      s += fxor<0xB1>(s);                                                    \
      s += fxor<0x4E>(s);                                                    \
      const float e2 = __expf(s);                                            \
      sum += e2;                                                             \
      kp[(K) & 3] = (d == ((K) >> 2)) ? e2 : kp[(K) & 3];                    \
      const float2 v01 = h2f((V).y);                                         \
      const float2 v23 = h2f((V).w);                                         \
      a0 += e2 * v01.x; a1 += e2 * v01.y; a2 += e2 * v23.x; a3 += e2 * v23.y;\
    }
    CSTEP(kvA[0], 0)  CSTEP(kvA[1], 1)  CSTEP(kvA[2], 2)  CSTEP(kvA[3], 3)
    CSTEP(kvA[4], 4)  CSTEP(kvA[5], 5)  CSTEP(kvA[6], 6)  CSTEP(kvA[7], 7)
    asm volatile("s_waitcnt vmcnt(2)" ::: "memory");
    __builtin_amdgcn_sched_barrier(0);
    CSTEP(kvB[0], 8)  CSTEP(kvB[1], 9)  CSTEP(kvB[2], 10) CSTEP(kvB[3], 11)
    CSTEP(kvB[4], 12) CSTEP(kvB[5], 13) CSTEP(kvB[6], 14) CSTEP(kvB[7], 15)
#undef CSTEP

    const float inv = 1.f / sum;
    atomicAdd(&lcent[idq.x], kp[0] * inv);
    atomicAdd(&lcent[idq.y], kp[1] * inv);
    atomicAdd(&lcent[idq.z], kp[2] * inv);
    atomicAdd(&lcent[idq.w], kp[3] * inv);

    float* fb = feat + ((size_t)b * CHAN + 8 * DIM + 4 * d) * NPTS + n;
    __builtin_nontemporal_store(a0 * inv, fb);
    __builtin_nontemporal_store(a1 * inv, fb + NPTS);
    __builtin_nontemporal_store(a2 * inv, fb + 2 * NPTS);
    __builtin_nontemporal_store(a3 * inv, fb + 3 * NPTS);

    asm volatile("s_waitcnt vmcnt(4)" ::: "memory");
    __builtin_amdgcn_sched_barrier(0);
    n = nn; idq = idqn; qq = qqn;
  }
  asm volatile("s_waitcnt vmcnt(0)" ::: "memory");
  __builtin_amdgcn_sched_barrier(0);

  __syncthreads();
  f4v* p4 = (f4v*)(partB + (size_t)(b * PCHB + chunk) * NPTS);
  #pragma unroll
  for (int i2 = 0; i2 < NPTS / 4 / 512; ++i2) {
    const int j2 = (i2 * 512 + tid + chunk * 128) & 4095;
    __builtin_nontemporal_store(l4[j2], &p4[j2]);
  }
}

// cent[b,g,m]: g<8 from partA (16 slice-pairs), g=8 from partB (32 slices).
__global__ __launch_bounds__(256) void reduce_cent_kernel(
    const float* __restrict__ partA, const float* __restrict__ partB,
    float* __restrict__ cent) {
  const int t = blockIdx.x * 256 + threadIdx.x;  // over 36 * 4096
  const int bg = t >> 12;
  const int m4 = (t & 4095) << 2;
  const int b = bg / GRP, g = bg - b * GRP;
  f4v s = (f4v){0.f, 0.f, 0.f, 0.f};
  if (g < 8) {
    const int PU = b * 4 + (g >> 1), gh = g & 1;
    const f4v* p = (const f4v*)(partA + ((size_t)(PU * PCHA) * 2 + gh) * NPTS + m4);
    #pragma unroll
    for (int i = 0; i < PCHA; ++i)
      s += __builtin_nontemporal_load(&p[(size_t)i * 2 * (NPTS / 4)]);
  } else {
    const f4v* p = (const f4v*)(partB + (size_t)(b * PCHB) * NPTS + m4);
    #pragma unroll
    for (int i = 0; i < PCHB; ++i)
      s += __builtin_nontemporal_load(&p[(size_t)i * (NPTS / 4)]);
  }
  *(f4v*)(cent + (size_t)bg * NPTS + m4) = s;
}

extern "C" void kernel_launch(void* const* d_in, const int* in_sizes, int n_in,
                              void* d_out, int out_size, void* d_ws, size_t ws_size,
                              hipStream_t stream) {
  const float* q   = (const float*)d_in[0];
  const float* v   = (const float*)d_in[1];
  const int*   idx = (const int*)d_in[2];

  float* feat = (float*)d_out;                       // (B,C,N)
  float* cent = feat + (size_t)BATCH * CHAN * NPTS;  // (B,G,N)

  unsigned int* qvT = (unsigned int*)d_ws;                        // 41.9 MB
  float* partA = (float*)(qvT + (size_t)BATCH * NPTS * ROWU2);    // 32 MB
  float* partB = partA + (size_t)16 * PCHA * 2 * NPTS;            // 8 MB

  // 1) pack q,v into padded 640B rows
  dim3 tg(NPTS / TT, (CHAN + TT - 1) / TT, BATCH);
  pack_qv_kernel<<<tg, 256, 0, stream>>>(q, v, qvT);

  // 2a) group-pairs (g=0..7): 256 blocks x 512 thr, 128KB dyn LDS, 1/CU
  gtl_pair_kernel<<<256, 512, 2 * NPTS * sizeof(float), stream>>>(
      qvT, idx, feat, partA);

  // 2b) group 8: 128 blocks x 512 thr, 64KB LDS (R11 64B path)
  gtl_g8_kernel<<<128, 512, 0, stream>>>(qvT, idx, feat, partB);

  // 3) reduce partials -> cent
  reduce_cent_kernel<<<(NPAIR * NPTS / 4) / 256, 256, 0, stream>>>(
      partA, partB, cent);
}

// Round 13
// 199.047 us; speedup vs baseline: 2.9438x; 1.0558x over previous
//
#include <hip/hip_runtime.h>
#include <hip/hip_fp16.h>

// Problem constants (fixed by setup_inputs / GTLModuleV1)
#define BATCH 4
#define CHAN  144
#define NPTS  16384
#define KNN   16
#define GRP   9
#define DIM   16
#define ROWU2 160                // padded row: 144 data uints + 16 pad = 640 B
#define PCHA  16                 // pair-chunks per PU (1024 pts each)
#define PCHB  64                 // g8-chunks per batch (256 pts each)
#define NPAIR (BATCH * GRP)      // 36

#define TT 32

typedef __attribute__((ext_vector_type(2))) _Float16 h2v;
typedef __attribute__((ext_vector_type(4))) float    f4v;
typedef __attribute__((ext_vector_type(4))) int      i4v;
typedef __attribute__((ext_vector_type(4))) unsigned u4v;
__device__ __forceinline__ h2v as_h2(unsigned int u) {
  union { unsigned int u; h2v h; } c; c.u = u; return c.h;
}
__device__ __forceinline__ float2 h2f(unsigned u) {
  union { unsigned u; __half2 h; } c; c.u = u;
  return __half22float2(c.h);
}

// DPP helpers (quad_perm = VALU, no LDS pipe).
template<int J>
__device__ __forceinline__ int ibcast(int v) {
  return __builtin_amdgcn_update_dpp(0, v, (J) * 0x55, 0xF, 0xF, true);
}
template<int C>
__device__ __forceinline__ float fxor(float x) {
  int r = __builtin_amdgcn_update_dpp(0, __builtin_bit_cast(int, x), C, 0xF, 0xF, true);
  return __builtin_bit_cast(float, r);
}

// (C,N) fp32 q,v -> (N, 160 uints, 640B rows, 128B-aligned group-pairs).
__global__ __launch_bounds__(256) void pack_qv_kernel(
    const float* __restrict__ q, const float* __restrict__ v,
    unsigned int* __restrict__ qvT) {
  __shared__ float tq[TT][TT + 1];
  __shared__ float tv[TT][TT + 1];
  const int b = blockIdx.z;
  const float* qb = q + (size_t)b * CHAN * NPTS;
  const float* vb = v + (size_t)b * CHAN * NPTS;
  unsigned int* out = qvT + (size_t)b * NPTS * ROWU2;
  const int n0 = blockIdx.x * TT;
  const int c0 = blockIdx.y * TT;
  const int t = threadIdx.x;

  {  // load both tiles: float4 along n (coalesced)
    const int cl = t >> 3, nq = (t & 7) * 4;
    const int c = c0 + cl;
    if (c < CHAN) {
      const float4 a = *(const float4*)&qb[(size_t)c * NPTS + n0 + nq];
      tq[cl][nq + 0] = a.x; tq[cl][nq + 1] = a.y;
      tq[cl][nq + 2] = a.z; tq[cl][nq + 3] = a.w;
      const float4 w = *(const float4*)&vb[(size_t)c * NPTS + n0 + nq];
      tv[cl][nq + 0] = w.x; tv[cl][nq + 1] = w.y;
      tv[cl][nq + 2] = w.z; tv[cl][nq + 3] = w.w;
    }
  }
  __syncthreads();
  {  // store packed dim-pairs: uint4 along c
    const int nl = t >> 3, cq = (t & 7) * 4;
    const int c = c0 + cq;   // multiple of 4
    if (c < CHAN) {
      __half2 k01 = __halves2half2(__float2half_rn(tq[cq + 0][nl]),
                                   __float2half_rn(tq[cq + 1][nl]));
      __half2 v01 = __halves2half2(__float2half_rn(tv[cq + 0][nl]),
                                   __float2half_rn(tv[cq + 1][nl]));
      __half2 k23 = __halves2half2(__float2half_rn(tq[cq + 2][nl]),
                                   __float2half_rn(tq[cq + 3][nl]));
      __half2 v23 = __halves2half2(__float2half_rn(tv[cq + 2][nl]),
                                   __float2half_rn(tv[cq + 3][nl]));
      *(uint4*)&out[(size_t)(n0 + nl) * ROWU2 + c] =
          make_uint4(*(unsigned int*)&k01, *(unsigned int*)&v01,
                     *(unsigned int*)&k23, *(unsigned int*)&v23);
    }
  }
}

// R13 fused kernel. Blocks 0..255: group-PAIR path (R12 core, 1024thr =
// 16 waves -> 2x waves/CU vs R12's 8; (1024,4) caps VGPR at 128 so the
// ~52-reg core cannot spill — R9's (1024,8) cap-64 spill excluded).
// Blocks 256..511: g8 path (256 pts/block, single iteration) backfills
// the CUs as pair blocks finish — replaces R12's serial half-empty
// 128-block kernel (~24us) with ~8us of overlapped tail.
// Shared structure: forced-asm 18-deep gather pipeline (R11), counted
// vmcnt waits, DPP quad broadcast/butterfly, no-max softmax, LDS cent
// privatization (R8: global atomics bypass the non-coherent XCD L2s),
// rotated nt flush to part buffers.
__global__ __launch_bounds__(1024, 4) void gtl_fused_kernel(
    const unsigned int* __restrict__ qvT,  // (B, N, ROWU2)
    const int*   __restrict__ idx,         // (B, N, K)
    float* __restrict__ feat,              // (B, C, N)
    float* __restrict__ partA,             // (16, PCHA, 2, NPTS)
    float* __restrict__ partB)             // (BATCH, PCHB, NPTS)
{
  extern __shared__ float lcent[];         // 128 KB
  const int i = blockIdx.x;
  const int tid = threadIdx.x;
  f4v* l4 = (f4v*)lcent;

  if (i < 256) {
    // ================= pair path: groups 2j, 2j+1 =================
    // XCD map: PU = x + 8*(sblk>>4) -> 2 PUs/XCD = 4MB gather slices
    // exactly filling the XCD L2 (R12: FETCH 59MB ~= compulsory).
    const int x = i & 7, sblk = i >> 3;     // sblk 0..31
    const int PU = x + 8 * (sblk >> 4);
    const int chunk = sblk & 15;
    const int b = PU >> 2, j = PU & 3;

    #pragma unroll
    for (int ii = 0; ii < 2 * NPTS / 4 / 1024; ++ii)
      l4[ii * 1024 + tid] = (f4v){0.f, 0.f, 0.f, 0.f};
    __syncthreads();

    const int lane = tid & 63;
    const int wv   = tid >> 6;        // 16 waves
    const int slot = lane >> 3;       // point within wave [0,8)
    const int e    = lane & 7;        // 16B-slot within 128B pair-segment
    const int gh   = e >> 2;          // which group of the pair
    const int d    = e & 3;           // dim-quad within group

    const char* qvb  = (const char*)qvT + (size_t)b * NPTS * (ROWU2 * 4);
    const char* idxB = (const char*)idx + (size_t)b * NPTS * (KNN * 4);
    const unsigned laneB  = (unsigned)(j * 128 + e * 16);
    const unsigned idxoff = (unsigned)(d * 16);

    int n = chunk * 1024 + wv * 8 + slot;
    i4v idq; u4v qq;
    asm volatile("global_load_dwordx4 %0, %1, %2"
                 : "=v"(idq) : "v"((unsigned)n * 64u + idxoff), "s"(idxB));
    asm volatile("global_load_dwordx4 %0, %1, %2"
                 : "=v"(qq) : "v"((unsigned)n * (ROWU2 * 4u) + laneB), "s"(qvb));
    asm volatile("s_waitcnt vmcnt(0)" ::: "memory");
    __builtin_amdgcn_sched_barrier(0);

    for (int it = 0; it < 8; ++it) {   // 8 iters x 128 pts = 1024
      const h2v q01 = as_h2(qq.x);
      const h2v q23 = as_h2(qq.z);

      u4v kvA[8], kvB[8];
#define GISS(DST, K)                                                         \
      {                                                                      \
        const int mk = ibcast<((K) >> 2)>(                                   \
            ((K) & 3) == 0 ? idq.x : ((K) & 3) == 1 ? idq.y                  \
                           : ((K) & 3) == 2 ? idq.z : idq.w);                \
        const unsigned vo = (unsigned)mk * (ROWU2 * 4u) + laneB;             \
        asm volatile("global_load_dwordx4 %0, %1, %2"                        \
                     : "=v"(DST) : "v"(vo), "s"(qvb));                       \
      }
      GISS(kvA[0], 0)  GISS(kvA[1], 1)  GISS(kvA[2], 2)  GISS(kvA[3], 3)
      GISS(kvA[4], 4)  GISS(kvA[5], 5)  GISS(kvA[6], 6)  GISS(kvA[7], 7)
      GISS(kvB[0], 8)  GISS(kvB[1], 9)  GISS(kvB[2], 10) GISS(kvB[3], 11)
      GISS(kvB[4], 12) GISS(kvB[5], 13) GISS(kvB[6], 14) GISS(kvB[7], 15)
#undef GISS

      const int itn = (it + 1 < 8) ? it + 1 : it;
      const int nn = chunk * 1024 + itn * 128 + wv * 8 + slot;
      i4v idqn; u4v qqn;
      asm volatile("global_load_dwordx4 %0, %1, %2"
                   : "=v"(idqn) : "v"((unsigned)nn * 64u + idxoff), "s"(idxB));
      asm volatile("global_load_dwordx4 %0, %1, %2"
                   : "=v"(qqn) : "v"((unsigned)nn * (ROWU2 * 4u) + laneB), "s"(qvb));

      asm volatile("s_waitcnt vmcnt(10)" ::: "memory");
      __builtin_amdgcn_sched_barrier(0);

      float kp[4] = {0.f, 0.f, 0.f, 0.f};
      float sum = 0.f, a0 = 0.f, a1 = 0.f, a2 = 0.f, a3 = 0.f;
#define CSTEP(V, K)                                                          \
      {                                                                      \
        float s = __builtin_amdgcn_fdot2(as_h2((V).x), q01, 0.f, false);     \
        s = __builtin_amdgcn_fdot2(as_h2((V).z), q23, s, false);             \
        s += fxor<0xB1>(s);                                                  \
        s += fxor<0x4E>(s);                                                  \
        const float e2 = __expf(s);                                          \
        sum += e2;                                                           \
        kp[(K) & 3] = (d == ((K) >> 2)) ? e2 : kp[(K) & 3];                  \
        const float2 v01 = h2f((V).y);                                       \
        const float2 v23 = h2f((V).w);                                       \
        a0 += e2 * v01.x; a1 += e2 * v01.y;                                  \
        a2 += e2 * v23.x; a3 += e2 * v23.y;                                  \
      }
      CSTEP(kvA[0], 0)  CSTEP(kvA[1], 1)  CSTEP(kvA[2], 2)  CSTEP(kvA[3], 3)
      CSTEP(kvA[4], 4)  CSTEP(kvA[5], 5)  CSTEP(kvA[6], 6)  CSTEP(kvA[7], 7)

      asm volatile("s_waitcnt vmcnt(2)" ::: "memory");
      __builtin_amdgcn_sched_barrier(0);
      CSTEP(kvB[0], 8)  CSTEP(kvB[1], 9)  CSTEP(kvB[2], 10) CSTEP(kvB[3], 11)
      CSTEP(kvB[4], 12) CSTEP(kvB[5], 13) CSTEP(kvB[6], 14) CSTEP(kvB[7], 15)
#undef CSTEP

      const float inv = 1.f / sum;
      float* lc = lcent + gh * NPTS;
      atomicAdd(&lc[idq.x], kp[0] * inv);
      atomicAdd(&lc[idq.y], kp[1] * inv);
      atomicAdd(&lc[idq.z], kp[2] * inv);
      atomicAdd(&lc[idq.w], kp[3] * inv);

      float* fb = feat + ((size_t)b * CHAN + (2 * j + gh) * DIM + 4 * d) * NPTS + n;
      __builtin_nontemporal_store(a0 * inv, fb);
      __builtin_nontemporal_store(a1 * inv, fb + NPTS);
      __builtin_nontemporal_store(a2 * inv, fb + 2 * NPTS);
      __builtin_nontemporal_store(a3 * inv, fb + 3 * NPTS);

      asm volatile("s_waitcnt vmcnt(4)" ::: "memory");
      __builtin_amdgcn_sched_barrier(0);
      n = nn; idq = idqn; qq = qqn;
    }
    asm volatile("s_waitcnt vmcnt(0)" ::: "memory");
    __builtin_amdgcn_sched_barrier(0);

    __syncthreads();
    // flush both slices (rotated: PU's 16 blocks sweep disjoint regions)
    f4v* p4 = (f4v*)(partA + ((size_t)(PU * PCHA + chunk) * 2) * NPTS);
    #pragma unroll
    for (int i2 = 0; i2 < 2 * NPTS / 4 / 1024; ++i2) {
      const int j2 = (i2 * 1024 + tid + chunk * 512) & 8191;
      __builtin_nontemporal_store(l4[j2], &p4[j2]);
    }
  } else {
    // ================= g8 path: 256 pts, single iteration =================
    // XCD map: batch b on XCD pair {2b, 2b+1} (1MB g8 slice, L2-friendly).
    const int i2b = i - 256;
    const int x = i2b & 7, s = i2b >> 3;    // s 0..31
    const int b = x >> 1;
    const int chunk = s + 32 * (x & 1);     // 0..63

    #pragma unroll
    for (int ii = 0; ii < NPTS / 4 / 1024; ++ii)
      l4[ii * 1024 + tid] = (f4v){0.f, 0.f, 0.f, 0.f};
    __syncthreads();

    const int lane = tid & 63;
    const int wv   = tid >> 6;              // 16 waves
    const int slot = lane >> 2;             // 16 points / wave
    const int d    = lane & 3;

    const char* qvb  = (const char*)qvT + (size_t)b * NPTS * (ROWU2 * 4);
    const char* idxB = (const char*)idx + (size_t)b * NPTS * (KNN * 4);
    const unsigned laneB  = (unsigned)(8 * 64 + d * 16);  // group-8 slice
    const unsigned idxoff = (unsigned)(d * 16);

    const int n = chunk * 256 + wv * 16 + slot;
    i4v idq; u4v qq;
    asm volatile("global_load_dwordx4 %0, %1, %2"
                 : "=v"(idq) : "v"((unsigned)n * 64u + idxoff), "s"(idxB));
    asm volatile("global_load_dwordx4 %0, %1, %2"
                 : "=v"(qq) : "v"((unsigned)n * (ROWU2 * 4u) + laneB), "s"(qvb));
    asm volatile("s_waitcnt vmcnt(0)" ::: "memory");
    __builtin_amdgcn_sched_barrier(0);

    const h2v q01 = as_h2(qq.x);
    const h2v q23 = as_h2(qq.z);

    u4v kvA[8], kvB[8];
#define GISS(DST, K)                                                         \
    {                                                                        \
      const int mk = ibcast<((K) >> 2)>(                                     \
          ((K) & 3) == 0 ? idq.x : ((K) & 3) == 1 ? idq.y                    \
                         : ((K) & 3) == 2 ? idq.z : idq.w);                  \
      const unsigned vo = (unsigned)mk * (ROWU2 * 4u) + laneB;               \
      asm volatile("global_load_dwordx4 %0, %1, %2"                          \
                   : "=v"(DST) : "v"(vo), "s"(qvb));                         \
    }
    GISS(kvA[0], 0)  GISS(kvA[1], 1)  GISS(kvA[2], 2)  GISS(kvA[3], 3)
    GISS(kvA[4], 4)  GISS(kvA[5], 5)  GISS(kvA[6], 6)  GISS(kvA[7], 7)
    GISS(kvB[0], 8)  GISS(kvB[1], 9)  GISS(kvB[2], 10) GISS(kvB[3], 11)
    GISS(kvB[4], 12) GISS(kvB[5], 13) GISS(kvB[6], 14) GISS(kvB[7], 15)
#undef GISS

    asm volatile("s_waitcnt vmcnt(8)" ::: "memory");
    __builtin_amdgcn_sched_barrier(0);

    float kp[4] = {0.f, 0.f, 0.f, 0.f};
    float sum = 0.f, a0 = 0.f, a1 = 0.f, a2 = 0.f, a3 = 0.f;
#define CSTEP(V, K)                                                          \
    {                                                                        \
      float sc = __builtin_amdgcn_fdot2(as_h2((V).x), q01, 0.f, false);      \
      sc = __builtin_amdgcn_fdot2(as_h2((V).z), q23, sc, false);             \
      sc += fxor<0xB1>(sc);                                                  \
      sc += fxor<0x4E>(sc);                                                  \
      const float e2 = __expf(sc);                                           \
      sum += e2;                                                             \
      kp[(K) & 3] = (d == ((K) >> 2)) ? e2 : kp[(K) & 3];                    \
      const float2 v01 = h2f((V).y);                                         \
      const float2 v23 = h2f((V).w);                                         \
      a0 += e2 * v01.x; a1 += e2 * v01.y;                                    \
      a2 += e2 * v23.x; a3 += e2 * v23.y;                                    \
    }
    CSTEP(kvA[0], 0)  CSTEP(kvA[1], 1)  CSTEP(kvA[2], 2)  CSTEP(kvA[3], 3)
    CSTEP(kvA[4], 4)  CSTEP(kvA[5], 5)  CSTEP(kvA[6], 6)  CSTEP(kvA[7], 7)
    asm volatile("s_waitcnt vmcnt(0)" ::: "memory");
    __builtin_amdgcn_sched_barrier(0);
    CSTEP(kvB[0], 8)  CSTEP(kvB[1], 9)  CSTEP(kvB[2], 10) CSTEP(kvB[3], 11)
    CSTEP(kvB[4], 12) CSTEP(kvB[5], 13) CSTEP(kvB[6], 14) CSTEP(kvB[7], 15)
#undef CSTEP

    const float inv = 1.f / sum;
    atomicAdd(&lcent[idq.x], kp[0] * inv);
    atomicAdd(&lcent[idq.y], kp[1] * inv);
    atomicAdd(&lcent[idq.z], kp[2] * inv);
    atomicAdd(&lcent[idq.w], kp[3] * inv);

    float* fb = feat + ((size_t)b * CHAN + 8 * DIM + 4 * d) * NPTS + n;
    __builtin_nontemporal_store(a0 * inv, fb);
    __builtin_nontemporal_store(a1 * inv, fb + NPTS);
    __builtin_nontemporal_store(a2 * inv, fb + 2 * NPTS);
    __builtin_nontemporal_store(a3 * inv, fb + 3 * NPTS);

    __syncthreads();
    f4v* p4 = (f4v*)(partB + (size_t)(b * PCHB + chunk) * NPTS);
    #pragma unroll
    for (int i2 = 0; i2 < NPTS / 4 / 1024; ++i2) {
      const int j2 = (i2 * 1024 + tid + chunk * 64) & 4095;
      __builtin_nontemporal_store(l4[j2], &p4[j2]);
    }
  }
}

// cent[b,g,m]: g<8 from partA (16 slice-pairs), g=8 from partB (64 slices).
__global__ __launch_bounds__(256) void reduce_cent_kernel(
    const float* __restrict__ partA, const float* __restrict__ partB,
    float* __restrict__ cent) {
  const int t = blockIdx.x * 256 + threadIdx.x;  // over 36 * 4096
  const int bg = t >> 12;
  const int m4 = (t & 4095) << 2;
  const int b = bg / GRP, g = bg - b * GRP;
  f4v s = (f4v){0.f, 0.f, 0.f, 0.f};
  if (g < 8) {
    const int PU = b * 4 + (g >> 1), gh = g & 1;
    const f4v* p = (const f4v*)(partA + ((size_t)(PU * PCHA) * 2 + gh) * NPTS + m4);
    #pragma unroll
    for (int i = 0; i < PCHA; ++i)
      s += __builtin_nontemporal_load(&p[(size_t)i * 2 * (NPTS / 4)]);
  } else {
    const f4v* p = (const f4v*)(partB + (size_t)(b * PCHB) * NPTS + m4);
    #pragma unroll
    for (int i = 0; i < PCHB; ++i)
      s += __builtin_nontemporal_load(&p[(size_t)i * (NPTS / 4)]);
  }
  *(f4v*)(cent + (size_t)bg * NPTS + m4) = s;
}

extern "C" void kernel_launch(void* const* d_in, const int* in_sizes, int n_in,
                              void* d_out, int out_size, void* d_ws, size_t ws_size,
                              hipStream_t stream) {
  const float* q   = (const float*)d_in[0];
  const float* v   = (const float*)d_in[1];
  const int*   idx = (const int*)d_in[2];

  float* feat = (float*)d_out;                       // (B,C,N)
  float* cent = feat + (size_t)BATCH * CHAN * NPTS;  // (B,G,N)

  unsigned int* qvT = (unsigned int*)d_ws;                        // 41.9 MB
  float* partA = (float*)(qvT + (size_t)BATCH * NPTS * ROWU2);    // 32 MB
  float* partB = partA + (size_t)16 * PCHA * 2 * NPTS;            // 16 MB

  // 1) pack q,v into padded 640B rows
  dim3 tg(NPTS / TT, (CHAN + TT - 1) / TT, BATCH);
  pack_qv_kernel<<<tg, 256, 0, stream>>>(q, v, qvT);

  // 2) fused main kernel: 512 blocks x 1024 thr, 128KB dyn LDS.
  //    Blocks 0..255 = pair path (long, dispatch first, 1/CU);
  //    blocks 256..511 = g8 path (short, backfill as CUs free).
  gtl_fused_kernel<<<512, 1024, 2 * NPTS * sizeof(float), stream>>>(
      qvT, idx, feat, partA, partB);

  // 3) reduce partials -> cent
  reduce_cent_kernel<<<(NPAIR * NPTS / 4) / 256, 256, 0, stream>>>(
      partA, partB, cent);
}